// Round 1
// baseline (1997.426 us; speedup 1.0000x reference)
//
#include <hip/hip_runtime.h>
#include <hip/hip_bf16.h>

#define S_ 4
#define H_ 1024
#define D_ 256
#define B_ 8
#define N_ 1024
#define R_ (B_*N_)   /* 8192 */
#define EPS_ 1e-8f

// ---------------- Kernel 1: projection GEMM ----------------
// Out[s,r,d] = sum_h X[r,h]*Wp[s,h,d] + bp[s,d]   for X in {hx, ha}
__global__ __launch_bounds__(256) void k_proj(
    const float* __restrict__ hx, const float* __restrict__ ha,
    const float* __restrict__ Wp, const float* __restrict__ bp,
    float* __restrict__ xsub, float* __restrict__ asub)
{
    const int s   = blockIdx.z >> 1;
    const int sel = blockIdx.z & 1;
    const float* __restrict__ X = sel ? ha : hx;
    float* __restrict__ Out = sel ? asub : xsub;

    const int dt = blockIdx.x * 64;
    const int rt = blockIdx.y * 64;
    const int tx = threadIdx.x, ty = threadIdx.y;
    const int t  = ty * 16 + tx;

    __shared__ float As[64][17];
    __shared__ float Bs[16][65];

    float c[4][4] = {};
    const float* __restrict__ Wps = Wp + (size_t)s * H_ * D_;

    for (int k0 = 0; k0 < H_; k0 += 16) {
        {   // A tile 64x16 (row-major [R,H])
            const int kk = t & 15;
            const int m0 = t >> 4;
            #pragma unroll
            for (int p = 0; p < 4; ++p) {
                const int m = p * 16 + m0;
                As[m][kk] = X[(size_t)(rt + m) * H_ + k0 + kk];
            }
        }
        {   // B tile 16x64 (Wp[s] row-major [H,D])
            const int dl  = t & 63;
            const int kk0 = t >> 6;
            #pragma unroll
            for (int p = 0; p < 4; ++p) {
                const int kk = p * 4 + kk0;
                Bs[kk][dl] = Wps[(size_t)(k0 + kk) * D_ + dt + dl];
            }
        }
        __syncthreads();
        #pragma unroll
        for (int kk = 0; kk < 16; ++kk) {
            float a[4], b[4];
            #pragma unroll
            for (int i = 0; i < 4; ++i) a[i] = As[ty * 4 + i][kk];
            #pragma unroll
            for (int j = 0; j < 4; ++j) b[j] = Bs[kk][tx * 4 + j];
            #pragma unroll
            for (int i = 0; i < 4; ++i)
                #pragma unroll
                for (int j = 0; j < 4; ++j)
                    c[i][j] = fmaf(a[i], b[j], c[i][j]);
        }
        __syncthreads();
    }
    #pragma unroll
    for (int i = 0; i < 4; ++i) {
        const int r = rt + ty * 4 + i;
        #pragma unroll
        for (int j = 0; j < 4; ++j) {
            const int d = dt + tx * 4 + j;
            Out[(size_t)s * R_ * D_ + (size_t)r * D_ + d] = c[i][j] + bp[s * D_ + d];
        }
    }
}

// ---------------- Kernel 2: norms ----------------
// First S*R waves: normalize xsub in place. Next S*R waves: store 1/max(||a||,eps).
__global__ __launch_bounds__(256) void k_norm(
    float* __restrict__ xsub, const float* __restrict__ asub,
    float* __restrict__ inv_na)
{
    const int wave = blockIdx.x * 4 + (threadIdx.x >> 6);
    const int lane = threadIdx.x & 63;
    const bool is_a = wave >= S_ * R_;
    const int row = is_a ? wave - S_ * R_ : wave;
    const float* src = is_a ? asub : xsub;
    const float4 v = ((const float4*)(src + (size_t)row * D_))[lane];
    float ss = v.x * v.x + v.y * v.y + v.z * v.z + v.w * v.w;
    #pragma unroll
    for (int off = 32; off >= 1; off >>= 1)
        ss += __shfl_xor(ss, off, 64);
    const float scale = 1.0f / fmaxf(sqrtf(ss), EPS_);
    if (is_a) {
        if (lane == 0) inv_na[row] = scale;
    } else {
        float4 o = make_float4(v.x * scale, v.y * scale, v.z * scale, v.w * scale);
        ((float4*)(xsub + (size_t)row * D_))[lane] = o;
    }
}

// ---------------- Kernel 3: sim + softmax(across s) -> w (bf16) ----------------
__global__ __launch_bounds__(256) void k_sim(
    const float* __restrict__ xn, const float* __restrict__ asub,
    const float* __restrict__ inv_na, __hip_bfloat16* __restrict__ w)
{
    const int b  = blockIdx.z;
    const int it = blockIdx.y * 32;
    const int jt = blockIdx.x * 32;
    const int tx = threadIdx.x, ty = threadIdx.y;
    const int t  = ty * 16 + tx;

    __shared__ float Xs[32][33];
    __shared__ float Ays[32][33];

    float acc[S_][2][2] = {};

    for (int s = 0; s < S_; ++s) {
        const float* __restrict__ xb = xn   + (size_t)s * R_ * D_ + (size_t)(b * N_) * D_;
        const float* __restrict__ ab = asub + (size_t)s * R_ * D_ + (size_t)(b * N_) * D_;
        for (int k0 = 0; k0 < D_; k0 += 32) {
            {
                const int dl = t & 31;
                const int m0 = t >> 5;  // 0..7
                #pragma unroll
                for (int p = 0; p < 4; ++p) {
                    const int m = p * 8 + m0;
                    Xs[m][dl]  = xb[(size_t)(it + m) * D_ + k0 + dl];
                    Ays[m][dl] = ab[(size_t)(jt + m) * D_ + k0 + dl];
                }
            }
            __syncthreads();
            #pragma unroll
            for (int kk = 0; kk < 32; ++kk) {
                const float x0 = Xs[ty][kk],      x1 = Xs[ty + 16][kk];
                const float a0 = Ays[tx][kk],     a1 = Ays[tx + 16][kk];
                acc[s][0][0] = fmaf(x0, a0, acc[s][0][0]);
                acc[s][0][1] = fmaf(x0, a1, acc[s][0][1]);
                acc[s][1][0] = fmaf(x1, a0, acc[s][1][0]);
                acc[s][1][1] = fmaf(x1, a1, acc[s][1][1]);
            }
            __syncthreads();
        }
    }

    #pragma unroll
    for (int jj = 0; jj < 2; ++jj) {
        const int j = jt + tx + jj * 16;
        float inv[S_];
        #pragma unroll
        for (int s = 0; s < S_; ++s) inv[s] = inv_na[s * R_ + b * N_ + j];
        #pragma unroll
        for (int ii = 0; ii < 2; ++ii) {
            const int i = it + ty + ii * 16;
            float v[S_];
            float mx = -1e30f;
            #pragma unroll
            for (int s = 0; s < S_; ++s) { v[s] = acc[s][ii][jj] * inv[s]; mx = fmaxf(mx, v[s]); }
            float sum = 0.f;
            #pragma unroll
            for (int s = 0; s < S_; ++s) { v[s] = __expf(v[s] - mx); sum += v[s]; }
            const float rs = 1.0f / sum;
            #pragma unroll
            for (int s = 0; s < S_; ++s)
                w[(size_t)s * B_ * N_ * N_ + (size_t)b * N_ * N_ + (size_t)i * N_ + j] =
                    __float2bfloat16(v[s] * rs);
        }
    }
}

// ---------------- Kernel 4: weighted = w @ a_sub (batched over s,b) ----------------
__global__ __launch_bounds__(256) void k_weighted(
    const __hip_bfloat16* __restrict__ w, const float* __restrict__ asub,
    float* __restrict__ weighted)
{
    const int sb = blockIdx.z;          // s*B + b
    const int s = sb >> 3, b = sb & 7;
    const int dt = blockIdx.x * 64;
    const int it = blockIdx.y * 64;
    const int tx = threadIdx.x, ty = threadIdx.y;
    const int t  = ty * 16 + tx;

    const __hip_bfloat16* __restrict__ wb = w + (size_t)s * B_ * N_ * N_ + (size_t)b * N_ * N_;
    const float* __restrict__ ab = asub + (size_t)s * R_ * D_ + (size_t)(b * N_) * D_;

    __shared__ float As[64][17];
    __shared__ float Bs[16][65];
    float c[4][4] = {};

    for (int k0 = 0; k0 < N_; k0 += 16) {
        {
            const int kk = t & 15;
            const int m0 = t >> 4;
            #pragma unroll
            for (int p = 0; p < 4; ++p) {
                const int m = p * 16 + m0;
                As[m][kk] = __bfloat162float(wb[(size_t)(it + m) * N_ + k0 + kk]);
            }
        }
        {
            const int dl  = t & 63;
            const int kk0 = t >> 6;
            #pragma unroll
            for (int p = 0; p < 4; ++p) {
                const int kk = p * 4 + kk0;
                Bs[kk][dl] = ab[(size_t)(k0 + kk) * D_ + dt + dl];
            }
        }
        __syncthreads();
        #pragma unroll
        for (int kk = 0; kk < 16; ++kk) {
            float a[4], bb[4];
            #pragma unroll
            for (int i = 0; i < 4; ++i) a[i] = As[ty * 4 + i][kk];
            #pragma unroll
            for (int j = 0; j < 4; ++j) bb[j] = Bs[kk][tx * 4 + j];
            #pragma unroll
            for (int i = 0; i < 4; ++i)
                #pragma unroll
                for (int j = 0; j < 4; ++j)
                    c[i][j] = fmaf(a[i], bb[j], c[i][j]);
        }
        __syncthreads();
    }
    #pragma unroll
    for (int i = 0; i < 4; ++i) {
        const int r = b * N_ + it + ty * 4 + i;
        #pragma unroll
        for (int j = 0; j < 4; ++j) {
            const int d = dt + tx * 4 + j;
            weighted[(size_t)s * R_ * D_ + (size_t)r * D_ + d] = c[i][j];
        }
    }
}

// ---------------- Kernel 5: reconstruct ----------------
// out[r,h] = sum_{k=(s,d)} weighted[s,r,d] * Wr[k,h] + sum_s br[s,h]
__global__ __launch_bounds__(256) void k_recon(
    const float* __restrict__ weighted, const float* __restrict__ Wr,
    const float* __restrict__ br, float* __restrict__ out)
{
    const int ht = blockIdx.x * 64;
    const int rt = blockIdx.y * 64;
    const int tx = threadIdx.x, ty = threadIdx.y;
    const int t  = ty * 16 + tx;

    __shared__ float As[64][17];
    __shared__ float Bs[16][65];
    float c[4][4] = {};

    for (int k0 = 0; k0 < S_ * D_; k0 += 16) {
        const int sblk = k0 >> 8;       // which s (16-chunks never cross s boundary)
        const int d0   = k0 & 255;
        {
            const int kk = t & 15;
            const int m0 = t >> 4;
            #pragma unroll
            for (int p = 0; p < 4; ++p) {
                const int m = p * 16 + m0;
                As[m][kk] = weighted[(size_t)sblk * R_ * D_ + (size_t)(rt + m) * D_ + d0 + kk];
            }
        }
        {
            const int hl  = t & 63;
            const int kk0 = t >> 6;
            #pragma unroll
            for (int p = 0; p < 4; ++p) {
                const int kk = p * 4 + kk0;
                Bs[kk][hl] = Wr[(size_t)(k0 + kk) * H_ + ht + hl];
            }
        }
        __syncthreads();
        #pragma unroll
        for (int kk = 0; kk < 16; ++kk) {
            float a[4], bb[4];
            #pragma unroll
            for (int i = 0; i < 4; ++i) a[i] = As[ty * 4 + i][kk];
            #pragma unroll
            for (int j = 0; j < 4; ++j) bb[j] = Bs[kk][tx * 4 + j];
            #pragma unroll
            for (int i = 0; i < 4; ++i)
                #pragma unroll
                for (int j = 0; j < 4; ++j)
                    c[i][j] = fmaf(a[i], bb[j], c[i][j]);
        }
        __syncthreads();
    }
    #pragma unroll
    for (int i = 0; i < 4; ++i) {
        const int r = rt + ty * 4 + i;
        #pragma unroll
        for (int j = 0; j < 4; ++j) {
            const int h = ht + tx * 4 + j;
            const float bsum = br[0 * H_ + h] + br[1 * H_ + h] + br[2 * H_ + h] + br[3 * H_ + h];
            out[(size_t)r * H_ + h] = c[i][j] + bsum;
        }
    }
}

extern "C" void kernel_launch(void* const* d_in, const int* in_sizes, int n_in,
                              void* d_out, int out_size, void* d_ws, size_t ws_size,
                              hipStream_t stream) {
    const float* hx = (const float*)d_in[0];
    const float* ha = (const float*)d_in[1];
    const float* Wp = (const float*)d_in[2];
    const float* bp = (const float*)d_in[3];
    const float* Wr = (const float*)d_in[4];
    const float* br = (const float*)d_in[5];
    float* out = (float*)d_out;

    // Workspace layout (≈128.1 MiB):
    //   xsub   : S*R*D f32 (becomes xn in-place; reused as `weighted` after k_sim)
    //   asub   : S*R*D f32
    //   inv_na : S*R   f32
    //   w      : S*B*N*N bf16
    float* xsub = (float*)d_ws;
    float* asub = xsub + (size_t)S_ * R_ * D_;
    float* inv_na = asub + (size_t)S_ * R_ * D_;
    __hip_bfloat16* w = (__hip_bfloat16*)(inv_na + (size_t)S_ * R_);
    float* weighted = xsub;   // alias: xn is dead after k_sim

    dim3 blk(16, 16);

    // 1) projections: x_sub, a_sub
    k_proj<<<dim3(D_ / 64, R_ / 64, S_ * 2), blk, 0, stream>>>(hx, ha, Wp, bp, xsub, asub);

    // 2) norms: xn in place, inv_na for a
    k_norm<<<dim3(2 * S_ * R_ / 4), dim3(256), 0, stream>>>(xsub, asub, inv_na);

    // 3) sim + softmax across s -> w (bf16)
    k_sim<<<dim3(N_ / 32, N_ / 32, B_), blk, 0, stream>>>(xsub, asub, inv_na, w);

    // 4) weighted = w @ a_sub  (writes into xsub alias)
    k_weighted<<<dim3(D_ / 64, N_ / 64, S_ * B_), blk, 0, stream>>>(w, asub, weighted);

    // 5) reconstruct + bias
    k_recon<<<dim3(H_ / 64, R_ / 64), blk, 0, stream>>>(weighted, Wr, br, out);
}

// Round 2
// 227.074 us; speedup vs baseline: 8.7964x; 8.7964x over previous
//
#include <hip/hip_runtime.h>
#include <hip/hip_bf16.h>

#define S_ 4
#define H_ 1024
#define D_ 256
#define B_ 8
#define N_ 1024
#define R_ (B_*N_)   /* 8192 */
#define EPS_ 1e-8f

typedef float f32x4 __attribute__((ext_vector_type(4)));
typedef short bf16x8 __attribute__((ext_vector_type(8)));
typedef unsigned short u16;

__device__ __forceinline__ u16 f2b(float f) {
    union { __bf16 h; u16 u; } cv; cv.h = (__bf16)f; return cv.u;
}

__device__ __forceinline__ void gload16(const void* g, void* l) {
    __builtin_amdgcn_global_load_lds((const __attribute__((address_space(1))) void*)g,
                                     (__attribute__((address_space(3))) void*)l, 16, 0, 0);
}

// ---------------- prep: fp32 -> bf16 cast (8 elems/thread) ----------------
__global__ __launch_bounds__(256) void k_cast8(const float* __restrict__ src,
                                               u16* __restrict__ dst, int n8) {
    const int i = blockIdx.x * 256 + threadIdx.x;
    if (i >= n8) return;
    const float4 v0 = ((const float4*)src)[2 * i];
    const float4 v1 = ((const float4*)src)[2 * i + 1];
    union { u16 u[8]; uint4 v; } o;
    o.u[0] = f2b(v0.x); o.u[1] = f2b(v0.y); o.u[2] = f2b(v0.z); o.u[3] = f2b(v0.w);
    o.u[4] = f2b(v1.x); o.u[5] = f2b(v1.y); o.u[6] = f2b(v1.z); o.u[7] = f2b(v1.w);
    ((uint4*)dst)[i] = o.v;
}

// ---------------- prep: 64x64 tiled transpose + cast ----------------
// src fp32 [*..][cols stride lds_], writes dst bf16 transposed (row stride ldd).
__device__ __forceinline__ void tc64(const float* __restrict__ src, int lds_,
                                     u16* __restrict__ dst, int ldd) {
    __shared__ float t[64][65];
    const int tid = threadIdx.x;
    const int rr = tid >> 4;          // 0..15
    const int cc = (tid & 15) * 4;    // 0..60
    #pragma unroll
    for (int p = 0; p < 4; ++p) {
        const int r = rr + p * 16;
        const float4 v = *(const float4*)(src + (size_t)r * lds_ + cc);
        t[r][cc] = v.x; t[r][cc + 1] = v.y; t[r][cc + 2] = v.z; t[r][cc + 3] = v.w;
    }
    __syncthreads();
    #pragma unroll
    for (int p = 0; p < 4; ++p) {
        const int c = rr + p * 16;    // output row (= src col)
        union { u16 u[4]; uint2 v; } o;
        o.u[0] = f2b(t[cc + 0][c]); o.u[1] = f2b(t[cc + 1][c]);
        o.u[2] = f2b(t[cc + 2][c]); o.u[3] = f2b(t[cc + 3][c]);
        *(uint2*)(dst + (size_t)c * ldd + cc) = o.v;
    }
}

__global__ __launch_bounds__(256) void k_tc_wp(const float* __restrict__ Wp, u16* __restrict__ WpT) {
    const int s = blockIdx.z;
    const int r0 = blockIdx.x * 64;   // h
    const int c0 = blockIdx.y * 64;   // d
    tc64(Wp + (size_t)s * H_ * D_ + (size_t)r0 * D_ + c0, D_,
         WpT + (size_t)s * D_ * H_ + (size_t)c0 * H_ + r0, H_);
}

__global__ __launch_bounds__(256) void k_tc_wr(const float* __restrict__ Wr, u16* __restrict__ WrT) {
    const int r0 = blockIdx.y * 64;   // sd
    const int c0 = blockIdx.x * 64;   // h
    tc64(Wr + (size_t)r0 * H_ + c0, H_,
         WrT + (size_t)c0 * H_ + r0, H_);
}

__global__ __launch_bounds__(256) void k_tc_asub(const float* __restrict__ asub, u16* __restrict__ asubT) {
    const int sb = blockIdx.z, s = sb >> 3, b = sb & 7;
    const int r0 = blockIdx.x * 64;   // j
    const int c0 = blockIdx.y * 64;   // d
    tc64(asub + ((size_t)(b * N_ + r0)) * 1024 + s * D_ + c0, 1024,
         asubT + ((size_t)sb << 18) + (size_t)c0 * N_ + r0, N_);
}

__global__ __launch_bounds__(256) void k_brsum(const float* __restrict__ br, float* __restrict__ bs) {
    const int h = blockIdx.x * 256 + threadIdx.x;
    if (h < H_) bs[h] = br[h] + br[H_ + h] + br[2 * H_ + h] + br[3 * H_ + h];
}

// ---------------- norm: per 256-seg L2 normalize, write bf16 ----------------
__global__ __launch_bounds__(256) void k_norm_bf16(const float* __restrict__ src, u16* __restrict__ dst) {
    const int widx = blockIdx.x * 4 + (threadIdx.x >> 6);   // (row, seg)
    const int l = threadIdx.x & 63;
    const size_t base = (size_t)(widx >> 2) * 1024 + (size_t)(widx & 3) * 256;
    const float4 v = *(const float4*)(src + base + l * 4);
    float ss = v.x * v.x + v.y * v.y + v.z * v.z + v.w * v.w;
    #pragma unroll
    for (int off = 32; off >= 1; off >>= 1) ss += __shfl_xor(ss, off, 64);
    const float sc = 1.0f / fmaxf(sqrtf(ss), EPS_);
    union { u16 u[4]; uint2 v2; } o;
    o.u[0] = f2b(v.x * sc); o.u[1] = f2b(v.y * sc);
    o.u[2] = f2b(v.z * sc); o.u[3] = f2b(v.w * sc);
    *(uint2*)(dst + base + l * 4) = o.v2;
}

// ---------------- m97-style 128x128 GEMM core: C = A(MxK) . B^T(NxK) ----------------
__device__ __forceinline__ void gemm128_core(
    const u16* __restrict__ A, const u16* __restrict__ B,
    int lda, int ldb, int K,
    u16* As, u16* Bs, f32x4 acc[4][4])
{
    const int tid = threadIdx.x;
    const int l = tid & 63, wv = tid >> 6;     // 4 waves
    const int wm = wv >> 1, wn = wv & 1;
    const int srow = (l >> 2);                 // 0..15
    const int scol = (l & 3) * 8;
    for (int k0 = 0; k0 < K; k0 += 32) {
        #pragma unroll
        for (int c = 0; c < 2; ++c) {
            const int row = c * 64 + wv * 16 + srow;
            gload16(A + (size_t)row * lda + k0 + scol, (char*)As + c * 4096 + wv * 1024);
            gload16(B + (size_t)row * ldb + k0 + scol, (char*)Bs + c * 4096 + wv * 1024);
        }
        __syncthreads();
        bf16x8 af[4], bfr[4];
        #pragma unroll
        for (int m = 0; m < 4; ++m)
            af[m] = *(const bf16x8*)(As + (wm * 64 + m * 16 + (l & 15)) * 32 + (l >> 4) * 8);
        #pragma unroll
        for (int n = 0; n < 4; ++n)
            bfr[n] = *(const bf16x8*)(Bs + (wn * 64 + n * 16 + (l & 15)) * 32 + (l >> 4) * 8);
        #pragma unroll
        for (int m = 0; m < 4; ++m)
            #pragma unroll
            for (int n = 0; n < 4; ++n)
                acc[m][n] = __builtin_amdgcn_mfma_f32_16x16x32_bf16(af[m], bfr[n], acc[m][n], 0, 0, 0);
        __syncthreads();
    }
}

// ---------------- proj: xsub/asub = (hxb|hab) . WpT^T + bp ----------------
__global__ __launch_bounds__(256) void k_gemm_proj(
    const u16* __restrict__ hxb, const u16* __restrict__ hab,
    const u16* __restrict__ WpT, const float* __restrict__ bp,
    float* __restrict__ xsub, float* __restrict__ asub)
{
    __shared__ u16 As[128 * 32], Bs[128 * 32];
    const u16* A = blockIdx.z ? hab : hxb;
    float* C = blockIdx.z ? asub : xsub;
    const int mt = blockIdx.y * 128, nt = blockIdx.x * 128;
    f32x4 acc[4][4];
    #pragma unroll
    for (int m = 0; m < 4; ++m)
        #pragma unroll
        for (int n = 0; n < 4; ++n) acc[m][n] = (f32x4){0.f, 0.f, 0.f, 0.f};
    gemm128_core(A + (size_t)mt * H_, WpT + (size_t)nt * H_, H_, H_, H_, As, Bs, acc);
    const int l = threadIdx.x & 63, wv = threadIdx.x >> 6;
    const int wm = wv >> 1, wn = wv & 1;
    #pragma unroll
    for (int m = 0; m < 4; ++m)
        #pragma unroll
        for (int n = 0; n < 4; ++n)
            #pragma unroll
            for (int q = 0; q < 4; ++q) {
                const int row = mt + wm * 64 + m * 16 + (l >> 4) * 4 + q;
                const int col = nt + wn * 64 + n * 16 + (l & 15);
                C[(size_t)row * 1024 + col] = acc[m][n][q] + bp[col];
            }
}

// ---------------- sim + softmax over s -> w (bf16) ----------------
__global__ __launch_bounds__(512) void k_sim_mfma(
    const u16* __restrict__ xnb, const u16* __restrict__ anb, u16* __restrict__ wout)
{
    __shared__ u16 As[128 * 32], Bs[128 * 32];
    const int b = blockIdx.z;
    const int it = blockIdx.y * 128, jt = blockIdx.x * 128;
    const int tid = threadIdx.x, l = tid & 63, wv = tid >> 6;   // 8 waves
    const int wi = wv >> 2, wj = wv & 3;                        // 2 x 4
    const u16* Abase = xnb + (size_t)(b * N_ + it) * 1024;
    const u16* Bbase = anb + (size_t)(b * N_ + jt) * 1024;
    f32x4 acc[4][4][2];   // [s][m][n]
    #pragma unroll
    for (int s = 0; s < 4; ++s)
        #pragma unroll
        for (int m = 0; m < 4; ++m)
            #pragma unroll
            for (int n = 0; n < 2; ++n) acc[s][m][n] = (f32x4){0.f, 0.f, 0.f, 0.f};

    const int srow = wv * 16 + (l >> 2);
    const int scol = (l & 3) * 8;
    #pragma unroll
    for (int s = 0; s < 4; ++s) {
        for (int k0 = s * 256; k0 < s * 256 + 256; k0 += 32) {
            gload16(Abase + (size_t)srow * 1024 + k0 + scol, (char*)As + wv * 1024);
            gload16(Bbase + (size_t)srow * 1024 + k0 + scol, (char*)Bs + wv * 1024);
            __syncthreads();
            bf16x8 af[4], bfr[2];
            #pragma unroll
            for (int m = 0; m < 4; ++m)
                af[m] = *(const bf16x8*)(As + (wi * 64 + m * 16 + (l & 15)) * 32 + (l >> 4) * 8);
            #pragma unroll
            for (int n = 0; n < 2; ++n)
                bfr[n] = *(const bf16x8*)(Bs + (wj * 32 + n * 16 + (l & 15)) * 32 + (l >> 4) * 8);
            #pragma unroll
            for (int m = 0; m < 4; ++m)
                #pragma unroll
                for (int n = 0; n < 2; ++n)
                    acc[s][m][n] = __builtin_amdgcn_mfma_f32_16x16x32_bf16(af[m], bfr[n], acc[s][m][n], 0, 0, 0);
            __syncthreads();
        }
    }

    #pragma unroll
    for (int m = 0; m < 4; ++m)
        #pragma unroll
        for (int n = 0; n < 2; ++n)
            #pragma unroll
            for (int q = 0; q < 4; ++q) {
                const int i = it + wi * 64 + m * 16 + (l >> 4) * 4 + q;
                const int j = jt + wj * 32 + n * 16 + (l & 15);
                const float e0 = __expf(acc[0][m][n][q]);
                const float e1 = __expf(acc[1][m][n][q]);
                const float e2 = __expf(acc[2][m][n][q]);
                const float e3 = __expf(acc[3][m][n][q]);
                const float rs = 1.0f / (e0 + e1 + e2 + e3);
                const size_t ij = (size_t)i * N_ + j;
                wout[((size_t)(0 * B_ + b) << 20) + ij] = f2b(e0 * rs);
                wout[((size_t)(1 * B_ + b) << 20) + ij] = f2b(e1 * rs);
                wout[((size_t)(2 * B_ + b) << 20) + ij] = f2b(e2 * rs);
                wout[((size_t)(3 * B_ + b) << 20) + ij] = f2b(e3 * rs);
            }
}

// ---------------- weighted = w . asubT^T (per s,b), bf16 out ----------------
__global__ __launch_bounds__(256) void k_gemm_weighted(
    const u16* __restrict__ w, const u16* __restrict__ asubT, u16* __restrict__ weighted)
{
    __shared__ u16 As[128 * 32], Bs[128 * 32];
    const int sb = blockIdx.z, s = sb >> 3, b = sb & 7;
    const int mt = blockIdx.y * 128, nt = blockIdx.x * 128;   // i, d
    f32x4 acc[4][4];
    #pragma unroll
    for (int m = 0; m < 4; ++m)
        #pragma unroll
        for (int n = 0; n < 4; ++n) acc[m][n] = (f32x4){0.f, 0.f, 0.f, 0.f};
    gemm128_core(w + ((size_t)sb << 20) + (size_t)mt * 1024,
                 asubT + ((size_t)sb << 18) + (size_t)nt * 1024,
                 1024, 1024, 1024, As, Bs, acc);
    const int l = threadIdx.x & 63, wv = threadIdx.x >> 6;
    const int wm = wv >> 1, wn = wv & 1;
    #pragma unroll
    for (int m = 0; m < 4; ++m)
        #pragma unroll
        for (int n = 0; n < 4; ++n)
            #pragma unroll
            for (int q = 0; q < 4; ++q) {
                const int i = mt + wm * 64 + m * 16 + (l >> 4) * 4 + q;
                const int d = nt + wn * 64 + n * 16 + (l & 15);
                weighted[(size_t)(b * N_ + i) * 1024 + s * 256 + d] = f2b(acc[m][n][q]);
            }
}

// ---------------- recon: out = weighted . WrT^T + brsum ----------------
__global__ __launch_bounds__(256) void k_gemm_recon(
    const u16* __restrict__ weighted, const u16* __restrict__ WrT,
    const float* __restrict__ brsum, float* __restrict__ out)
{
    __shared__ u16 As[128 * 32], Bs[128 * 32];
    const int mt = blockIdx.y * 128, nt = blockIdx.x * 128;
    f32x4 acc[4][4];
    #pragma unroll
    for (int m = 0; m < 4; ++m)
        #pragma unroll
        for (int n = 0; n < 4; ++n) acc[m][n] = (f32x4){0.f, 0.f, 0.f, 0.f};
    gemm128_core(weighted + (size_t)mt * 1024, WrT + (size_t)nt * 1024,
                 1024, 1024, 1024, As, Bs, acc);
    const int l = threadIdx.x & 63, wv = threadIdx.x >> 6;
    const int wm = wv >> 1, wn = wv & 1;
    #pragma unroll
    for (int m = 0; m < 4; ++m)
        #pragma unroll
        for (int n = 0; n < 4; ++n)
            #pragma unroll
            for (int q = 0; q < 4; ++q) {
                const int row = mt + wm * 64 + m * 16 + (l >> 4) * 4 + q;
                const int col = nt + wn * 64 + n * 16 + (l & 15);
                out[(size_t)row * 1024 + col] = acc[m][n][q] + brsum[col];
            }
}

extern "C" void kernel_launch(void* const* d_in, const int* in_sizes, int n_in,
                              void* d_out, int out_size, void* d_ws, size_t ws_size,
                              hipStream_t stream) {
    const float* hx = (const float*)d_in[0];
    const float* ha = (const float*)d_in[1];
    const float* Wp = (const float*)d_in[2];
    const float* bp = (const float*)d_in[3];
    const float* Wr = (const float*)d_in[4];
    const float* br = (const float*)d_in[5];
    float* out = (float*)d_out;

    const size_t MB = 1ull << 20;
    // Workspace map (<=120 MiB; phase-aliased):
    //  [0,16)   hxb      -> xnb       -> (dead)      [weighted overlaps? no: weighted=@0 after sim]
    //  [16,32)  hab      -> anb
    //  [32,34)  WpT   [34,36) WrT   [36,36.1) brsum
    //  [40,72)  xsub f32 -> asubT@[40,56) + w0@[56,72)
    //  [72,104) asub f32 -> w1,w2
    //  [104,120) w3
    u16* hxb = (u16*)d_ws;                          // @0
    u16* hab = hxb + (size_t)R_ * H_;               // @16
    u16* WpT = hab + (size_t)R_ * H_;               // @32
    u16* WrT = WpT + (size_t)H_ * H_;               // @34
    float* brsum = (float*)(WrT + (size_t)H_ * H_); // @36
    float* xsub = (float*)((char*)d_ws + 40 * MB);  // @40 (32 MiB)
    float* asub = (float*)((char*)d_ws + 72 * MB);  // @72 (32 MiB)
    u16* xnb = (u16*)d_ws;                          // @0  (over hxb, after proj)
    u16* anb = hab;                                 // @16 (over hab, after proj)
    u16* asubT = (u16*)xsub;                        // @40 (16 MiB, after norm-x)
    u16* wbuf = (u16*)((char*)d_ws + 56 * MB);      // @56 (64 MiB contiguous)
    u16* weighted = (u16*)d_ws;                     // @0  (over xnb, after sim)

    // 1) casts + transposes + brsum
    k_cast8<<<dim3(R_ * H_ / 8 / 256), dim3(256), 0, stream>>>(hx, hxb, R_ * H_ / 8);
    k_cast8<<<dim3(R_ * H_ / 8 / 256), dim3(256), 0, stream>>>(ha, hab, R_ * H_ / 8);
    k_tc_wp<<<dim3(16, 4, 4), dim3(256), 0, stream>>>(Wp, WpT);
    k_tc_wr<<<dim3(16, 16), dim3(256), 0, stream>>>(Wr, WrT);
    k_brsum<<<dim3(4), dim3(256), 0, stream>>>(br, brsum);

    // 2) projection GEMMs (bf16 MFMA, fp32 out + bias)
    k_gemm_proj<<<dim3(8, 64, 2), dim3(256), 0, stream>>>(hxb, hab, WpT, bp, xsub, asub);

    // 3) normalize (per 256-seg) -> bf16
    k_norm_bf16<<<dim3(R_ * S_ / 4), dim3(256), 0, stream>>>(xsub, xnb);
    k_norm_bf16<<<dim3(R_ * S_ / 4), dim3(256), 0, stream>>>(asub, anb);

    // 4) transpose asub -> asubT (bf16, per (s,b))
    k_tc_asub<<<dim3(16, 4, 32), dim3(256), 0, stream>>>(asub, asubT);

    // 5) sim + softmax(s) -> w
    k_sim_mfma<<<dim3(8, 8, 8), dim3(512), 0, stream>>>(xnb, anb, wbuf);

    // 6) weighted = w @ a_sub   (bf16 out, [r][s*256+d])
    k_gemm_weighted<<<dim3(2, 8, 32), dim3(256), 0, stream>>>(wbuf, asubT, weighted);

    // 7) reconstruct + bias
    k_gemm_recon<<<dim3(8, 64), dim3(256), 0, stream>>>(weighted, WrT, brsum, out);
}

// Round 3
// 200.538 us; speedup vs baseline: 9.9603x; 1.1323x over previous
//
#include <hip/hip_runtime.h>
#include <hip/hip_bf16.h>

#define S_ 4
#define H_ 1024
#define D_ 256
#define B_ 8
#define N_ 1024
#define R_ (B_*N_)   /* 8192 */
#define EPS_ 1e-8f

typedef float f32x4 __attribute__((ext_vector_type(4)));
typedef short bf16x8 __attribute__((ext_vector_type(8)));
typedef unsigned short u16;

__device__ __forceinline__ u16 f2b(float f) {
    union { __bf16 h; u16 u; } cv; cv.h = (__bf16)f; return cv.u;
}

__device__ __forceinline__ void gload16(const void* g, void* l) {
    __builtin_amdgcn_global_load_lds((const __attribute__((address_space(1))) void*)g,
                                     (__attribute__((address_space(3))) void*)l, 16, 0, 0);
}

// ---------------- prep: fp32 -> bf16 cast ----------------
__global__ __launch_bounds__(256) void k_cast8(const float* __restrict__ src,
                                               u16* __restrict__ dst, int n8) {
    const int i = blockIdx.x * 256 + threadIdx.x;
    if (i >= n8) return;
    const float4 v0 = ((const float4*)src)[2 * i];
    const float4 v1 = ((const float4*)src)[2 * i + 1];
    union { u16 u[8]; uint4 v; } o;
    o.u[0] = f2b(v0.x); o.u[1] = f2b(v0.y); o.u[2] = f2b(v0.z); o.u[3] = f2b(v0.w);
    o.u[4] = f2b(v1.x); o.u[5] = f2b(v1.y); o.u[6] = f2b(v1.z); o.u[7] = f2b(v1.w);
    ((uint4*)dst)[i] = o.v;
}

// ---------------- prep: 64x64 fp32 transpose + cast ----------------
__device__ __forceinline__ void tc64(const float* __restrict__ src, int lds_,
                                     u16* __restrict__ dst, int ldd) {
    __shared__ float t[64][65];
    const int tid = threadIdx.x;
    const int rr = tid >> 4;
    const int cc = (tid & 15) * 4;
    #pragma unroll
    for (int p = 0; p < 4; ++p) {
        const int r = rr + p * 16;
        const float4 v = *(const float4*)(src + (size_t)r * lds_ + cc);
        t[r][cc] = v.x; t[r][cc + 1] = v.y; t[r][cc + 2] = v.z; t[r][cc + 3] = v.w;
    }
    __syncthreads();
    #pragma unroll
    for (int p = 0; p < 4; ++p) {
        const int c = rr + p * 16;
        union { u16 u[4]; uint2 v; } o;
        o.u[0] = f2b(t[cc + 0][c]); o.u[1] = f2b(t[cc + 1][c]);
        o.u[2] = f2b(t[cc + 2][c]); o.u[3] = f2b(t[cc + 3][c]);
        *(uint2*)(dst + (size_t)c * ldd + cc) = o.v;
    }
}

__global__ __launch_bounds__(256) void k_tc_wp(const float* __restrict__ Wp, u16* __restrict__ WpT) {
    const int s = blockIdx.z;
    const int r0 = blockIdx.x * 64;   // h
    const int c0 = blockIdx.y * 64;   // d
    tc64(Wp + (size_t)s * H_ * D_ + (size_t)r0 * D_ + c0, D_,
         WpT + (size_t)s * D_ * H_ + (size_t)c0 * H_ + r0, H_);
}

__global__ __launch_bounds__(256) void k_tc_wr(const float* __restrict__ Wr, u16* __restrict__ WrT) {
    const int r0 = blockIdx.y * 64;   // sd
    const int c0 = blockIdx.x * 64;   // h
    tc64(Wr + (size_t)r0 * H_ + c0, H_,
         WrT + (size_t)c0 * H_ + r0, H_);
}

__global__ __launch_bounds__(256) void k_brsum(const float* __restrict__ br, float* __restrict__ bs) {
    const int h = blockIdx.x * 256 + threadIdx.x;
    if (h < H_) bs[h] = br[h] + br[H_ + h] + br[2 * H_ + h] + br[3 * H_ + h];
}

// ---------------- bf16 64x64 transpose: araw [r][s*256+d] -> arawT [(s,b)][d][j] ----------------
__global__ __launch_bounds__(256) void k_tc_araw(const u16* __restrict__ src, u16* __restrict__ dst) {
    const int sb = blockIdx.z, s = sb >> 3, b = sb & 7;
    const int j0 = blockIdx.x * 64, d0 = blockIdx.y * 64;
    __shared__ u16 tile[64][68];
    const int t = threadIdx.x;
    const int r = t >> 4, c4 = (t & 15) * 4;
    #pragma unroll
    for (int p = 0; p < 4; ++p) {
        const int row = p * 16 + r;
        *(uint2*)&tile[row][c4] =
            *(const uint2*)(src + (size_t)(b * N_ + j0 + row) * 1024 + s * 256 + d0 + c4);
    }
    __syncthreads();
    #pragma unroll
    for (int p = 0; p < 4; ++p) {
        const int orow = p * 16 + r;      // d-index
        union { u16 u[4]; uint2 v; } o;
        o.u[0] = tile[c4 + 0][orow]; o.u[1] = tile[c4 + 1][orow];
        o.u[2] = tile[c4 + 2][orow]; o.u[3] = tile[c4 + 3][orow];
        *(uint2*)(dst + ((size_t)sb << 18) + (size_t)(d0 + orow) * 1024 + j0 + c4) = o.v;
    }
}

// ---------------- proj (fused norm): 128x256 tile, BK=64, swizzled staging ----------------
// z=0: xnb = normalize(hx.WpT^T + bp)   z=1: araw = (ha.WpT^T + bp), inv_na
__global__ __launch_bounds__(512, 4) void k_proj_norm(
    const u16* __restrict__ hxb, const u16* __restrict__ hab,
    const u16* __restrict__ WpT, const float* __restrict__ bp,
    u16* __restrict__ xnb, u16* __restrict__ araw, float* __restrict__ inv_na)
{
    __shared__ u16 As[128 * 64];
    __shared__ u16 Bs[256 * 64];
    __shared__ float normbuf[128][4];

    const int is_a = blockIdx.z;
    const int s  = blockIdx.x;            // n-tile == subspace (256 cols)
    const int rt = blockIdx.y * 128;
    const int tid = threadIdx.x;
    const int l = tid & 63, wv = tid >> 6;    // 8 waves
    const int wm = wv >> 2, wn = wv & 3;      // 2 x 4 -> wave tile 64x64
    const u16* __restrict__ Ag = (is_a ? hab : hxb) + (size_t)rt * 1024;
    const u16* __restrict__ Bg = WpT + (size_t)(s * 256) * 1024;

    f32x4 acc[4][4];
    #pragma unroll
    for (int m = 0; m < 4; ++m)
        #pragma unroll
        for (int n = 0; n < 4; ++n) acc[m][n] = (f32x4){0.f, 0.f, 0.f, 0.f};

    for (int k0 = 0; k0 < 1024; k0 += 64) {
        #pragma unroll
        for (int i = 0; i < 2; ++i) {     // A: 128 rows x 8 chunks
            const int ci = i * 512 + tid;
            const int row = ci >> 3, c = ci & 7, cs = c ^ (row & 7);
            gload16(Ag + (size_t)row * 1024 + k0 + cs * 8, As + ci * 8);
        }
        #pragma unroll
        for (int i = 0; i < 4; ++i) {     // B: 256 rows x 8 chunks
            const int ci = i * 512 + tid;
            const int row = ci >> 3, c = ci & 7, cs = c ^ (row & 7);
            gload16(Bg + (size_t)row * 1024 + k0 + cs * 8, Bs + ci * 8);
        }
        __syncthreads();
        #pragma unroll
        for (int kc = 0; kc < 2; ++kc) {
            bf16x8 af[4], bfm[4];
            #pragma unroll
            for (int m = 0; m < 4; ++m) {
                const int r = wm * 64 + m * 16 + (l & 15);
                const int c = (kc * 4 + (l >> 4)) ^ (r & 7);
                af[m] = *(const bf16x8*)(As + r * 64 + c * 8);
            }
            #pragma unroll
            for (int n = 0; n < 4; ++n) {
                const int r = wn * 64 + n * 16 + (l & 15);
                const int c = (kc * 4 + (l >> 4)) ^ (r & 7);
                bfm[n] = *(const bf16x8*)(Bs + r * 64 + c * 8);
            }
            #pragma unroll
            for (int m = 0; m < 4; ++m)
                #pragma unroll
                for (int n = 0; n < 4; ++n)
                    acc[m][n] = __builtin_amdgcn_mfma_f32_16x16x32_bf16(af[m], bfm[n], acc[m][n], 0, 0, 0);
        }
        __syncthreads();
    }

    // ---- epilogue: bias, row L2-norm (over the 256 cols = full subspace), write bf16 ----
    float bv[4];
    #pragma unroll
    for (int n = 0; n < 4; ++n) bv[n] = bp[s * 256 + wn * 64 + n * 16 + (l & 15)];
    #pragma unroll
    for (int m = 0; m < 4; ++m)
        #pragma unroll
        for (int n = 0; n < 4; ++n)
            #pragma unroll
            for (int q = 0; q < 4; ++q) acc[m][n][q] += bv[n];

    float ss[4][4];
    #pragma unroll
    for (int m = 0; m < 4; ++m)
        #pragma unroll
        for (int q = 0; q < 4; ++q) {
            float v = 0.f;
            #pragma unroll
            for (int n = 0; n < 4; ++n) v += acc[m][n][q] * acc[m][n][q];
            ss[m][q] = v;
        }
    #pragma unroll
    for (int off = 1; off <= 8; off <<= 1)
        #pragma unroll
        for (int m = 0; m < 4; ++m)
            #pragma unroll
            for (int q = 0; q < 4; ++q) ss[m][q] += __shfl_xor(ss[m][q], off, 64);
    if ((l & 15) == 0) {
        #pragma unroll
        for (int m = 0; m < 4; ++m)
            #pragma unroll
            for (int q = 0; q < 4; ++q)
                normbuf[wm * 64 + m * 16 + (l >> 4) * 4 + q][wn] = ss[m][q];
    }
    __syncthreads();
    float sc[4][4];
    #pragma unroll
    for (int m = 0; m < 4; ++m)
        #pragma unroll
        for (int q = 0; q < 4; ++q) {
            const int rl = wm * 64 + m * 16 + (l >> 4) * 4 + q;
            const float tot = normbuf[rl][0] + normbuf[rl][1] + normbuf[rl][2] + normbuf[rl][3];
            sc[m][q] = 1.0f / fmaxf(sqrtf(tot), EPS_);
        }
    if (!is_a) {
        #pragma unroll
        for (int m = 0; m < 4; ++m)
            #pragma unroll
            for (int n = 0; n < 4; ++n)
                #pragma unroll
                for (int q = 0; q < 4; ++q) {
                    const int rl = wm * 64 + m * 16 + (l >> 4) * 4 + q;
                    xnb[(size_t)(rt + rl) * 1024 + s * 256 + wn * 64 + n * 16 + (l & 15)] =
                        f2b(acc[m][n][q] * sc[m][q]);
                }
    } else {
        #pragma unroll
        for (int m = 0; m < 4; ++m)
            #pragma unroll
            for (int n = 0; n < 4; ++n)
                #pragma unroll
                for (int q = 0; q < 4; ++q) {
                    const int rl = wm * 64 + m * 16 + (l >> 4) * 4 + q;
                    araw[(size_t)(rt + rl) * 1024 + s * 256 + wn * 64 + n * 16 + (l & 15)] =
                        f2b(acc[m][n][q]);
                }
        if (wn == 0 && (l & 15) == 0) {
            #pragma unroll
            for (int m = 0; m < 4; ++m)
                #pragma unroll
                for (int q = 0; q < 4; ++q) {
                    const int rl = wm * 64 + m * 16 + (l >> 4) * 4 + q;
                    inv_na[s * R_ + rt + rl] = sc[m][q];
                }
        }
    }
}

// ---------------- sim v2: dbuf BK=64, counted vmcnt, fused softmax(s) ----------------
__global__ __launch_bounds__(512) void k_sim_v2(
    const u16* __restrict__ xnb, const u16* __restrict__ araw,
    const float* __restrict__ inv_na, u16* __restrict__ whalf, const int half)
{
    __shared__ u16 SmA[2 * 128 * 64];
    __shared__ u16 SmB[2 * 128 * 64];
    const int b   = blockIdx.z;
    const int itl = blockIdx.y * 128;            // local to half (0..384)
    const int it  = half * 512 + itl;
    const int jt  = blockIdx.x * 128;
    const int tid = threadIdx.x, l = tid & 63, wv = tid >> 6;  // 8 waves
    const int wi = wv >> 2, wj = wv & 3;         // 2 x 4 -> wave tile 64x32 (per s)
    const u16* __restrict__ Ag = xnb  + (size_t)(b * N_ + it) * 1024;
    const u16* __restrict__ Bg = araw + (size_t)(b * N_ + jt) * 1024;

    f32x4 acc[4][4][2];  // [s][m][n]
    #pragma unroll
    for (int s = 0; s < 4; ++s)
        #pragma unroll
        for (int m = 0; m < 4; ++m)
            #pragma unroll
            for (int n = 0; n < 2; ++n) acc[s][m][n] = (f32x4){0.f, 0.f, 0.f, 0.f};

    auto STAGE = [&](int buf, int sS, int kkS) {
        const int k0 = sS * 256 + kkS * 64;
        u16* Ad = SmA + buf * 8192;
        u16* Bd = SmB + buf * 8192;
        #pragma unroll
        for (int i = 0; i < 2; ++i) {
            const int ci = i * 512 + tid;
            const int row = ci >> 3, c = ci & 7, cs = c ^ (row & 7);
            gload16(Ag + (size_t)row * 1024 + k0 + cs * 8, Ad + ci * 8);
            gload16(Bg + (size_t)row * 1024 + k0 + cs * 8, Bd + ci * 8);
        }
    };

    STAGE(0, 0, 0);
    #pragma unroll
    for (int s = 0; s < 4; ++s) {
        #pragma unroll
        for (int kk = 0; kk < 4; ++kk) {
            const int t = s * 4 + kk;
            const int cur = t & 1;
            if (t < 15) {
                const int tn = t + 1;
                STAGE(cur ^ 1, tn >> 2, tn & 3);
                asm volatile("s_waitcnt vmcnt(4)" ::: "memory");  // current tile landed; next 4 in flight
            } else {
                asm volatile("s_waitcnt vmcnt(0)" ::: "memory");
            }
            __builtin_amdgcn_s_barrier();           // all waves: current tile visible
            __builtin_amdgcn_sched_barrier(0);
            bf16x8 af[2][4], bfm[2][2];
            #pragma unroll
            for (int kc = 0; kc < 2; ++kc) {
                #pragma unroll
                for (int m = 0; m < 4; ++m) {
                    const int r = wi * 64 + m * 16 + (l & 15);
                    const int c = (kc * 4 + (l >> 4)) ^ (r & 7);
                    af[kc][m] = *(const bf16x8*)(SmA + cur * 8192 + r * 64 + c * 8);
                }
                #pragma unroll
                for (int n = 0; n < 2; ++n) {
                    const int r = wj * 32 + n * 16 + (l & 15);
                    const int c = (kc * 4 + (l >> 4)) ^ (r & 7);
                    bfm[kc][n] = *(const bf16x8*)(SmB + cur * 8192 + r * 64 + c * 8);
                }
            }
            asm volatile("s_waitcnt lgkmcnt(0)" ::: "memory");
            __builtin_amdgcn_s_barrier();           // reads done; buffer may be overwritten
            __builtin_amdgcn_sched_barrier(0);
            #pragma unroll
            for (int kc = 0; kc < 2; ++kc)
                #pragma unroll
                for (int m = 0; m < 4; ++m)
                    #pragma unroll
                    for (int n = 0; n < 2; ++n)
                        acc[s][m][n] = __builtin_amdgcn_mfma_f32_16x16x32_bf16(
                            af[kc][m], bfm[kc][n], acc[s][m][n], 0, 0, 0);
        }
    }

    // ---- epilogue: scale by inv_na[j], softmax over s, write w (bf16) ----
    const int ibase = itl + wi * 64;
    #pragma unroll
    for (int n = 0; n < 2; ++n) {
        const int jg = jt + wj * 32 + n * 16 + (l & 15);
        float inv[4];
        #pragma unroll
        for (int s = 0; s < 4; ++s) inv[s] = inv_na[s * R_ + b * N_ + jg];
        #pragma unroll
        for (int m = 0; m < 4; ++m)
            #pragma unroll
            for (int q = 0; q < 4; ++q) {
                const int il = ibase + m * 16 + (l >> 4) * 4 + q;
                float e[4]; float sum = 0.f;
                #pragma unroll
                for (int s = 0; s < 4; ++s) { e[s] = __expf(acc[s][m][n][q] * inv[s]); sum += e[s]; }
                const float rs = 1.0f / sum;
                #pragma unroll
                for (int s = 0; s < 4; ++s)
                    whalf[((size_t)(s * B_ + b) << 19) + (size_t)il * 1024 + jg] = f2b(e[s] * rs);
            }
    }
}

// ---------------- m97-style 128x128 core (unchanged, known-good) ----------------
__device__ __forceinline__ void gemm128_core(
    const u16* __restrict__ A, const u16* __restrict__ B,
    int lda, int ldb, int K,
    u16* As, u16* Bs, f32x4 acc[4][4])
{
    const int tid = threadIdx.x;
    const int l = tid & 63, wv = tid >> 6;
    const int wm = wv >> 1, wn = wv & 1;
    const int srow = (l >> 2);
    const int scol = (l & 3) * 8;
    for (int k0 = 0; k0 < K; k0 += 32) {
        #pragma unroll
        for (int c = 0; c < 2; ++c) {
            const int row = c * 64 + wv * 16 + srow;
            gload16(A + (size_t)row * lda + k0 + scol, (char*)As + c * 4096 + wv * 1024);
            gload16(B + (size_t)row * ldb + k0 + scol, (char*)Bs + c * 4096 + wv * 1024);
        }
        __syncthreads();
        bf16x8 af[4], bfr[4];
        #pragma unroll
        for (int m = 0; m < 4; ++m)
            af[m] = *(const bf16x8*)(As + (wm * 64 + m * 16 + (l & 15)) * 32 + (l >> 4) * 8);
        #pragma unroll
        for (int n = 0; n < 4; ++n)
            bfr[n] = *(const bf16x8*)(Bs + (wn * 64 + n * 16 + (l & 15)) * 32 + (l >> 4) * 8);
        #pragma unroll
        for (int m = 0; m < 4; ++m)
            #pragma unroll
            for (int n = 0; n < 4; ++n)
                acc[m][n] = __builtin_amdgcn_mfma_f32_16x16x32_bf16(af[m], bfr[n], acc[m][n], 0, 0, 0);
        __syncthreads();
    }
}

// ---------------- weighted = w_half . arawT^T (per s,b), bf16 out ----------------
__global__ __launch_bounds__(256) void k_gemm_weighted(
    const u16* __restrict__ whalf, const u16* __restrict__ arawT,
    u16* __restrict__ weighted, const int half)
{
    __shared__ u16 As[128 * 32], Bs[128 * 32];
    const int sb = blockIdx.z, s = sb >> 3, b = sb & 7;
    const int mt = blockIdx.y * 128, nt = blockIdx.x * 128;
    f32x4 acc[4][4];
    #pragma unroll
    for (int m = 0; m < 4; ++m)
        #pragma unroll
        for (int n = 0; n < 4; ++n) acc[m][n] = (f32x4){0.f, 0.f, 0.f, 0.f};
    gemm128_core(whalf + ((size_t)sb << 19) + (size_t)mt * 1024,
                 arawT + ((size_t)sb << 18) + (size_t)nt * 1024,
                 1024, 1024, 1024, As, Bs, acc);
    const int l = threadIdx.x & 63, wv = threadIdx.x >> 6;
    const int wm = wv >> 1, wn = wv & 1;
    #pragma unroll
    for (int m = 0; m < 4; ++m)
        #pragma unroll
        for (int n = 0; n < 4; ++n)
            #pragma unroll
            for (int q = 0; q < 4; ++q) {
                const int i = half * 512 + mt + wm * 64 + m * 16 + (l >> 4) * 4 + q;
                const int d = nt + wn * 64 + n * 16 + (l & 15);
                weighted[(size_t)(b * N_ + i) * 1024 + s * 256 + d] = f2b(acc[m][n][q]);
            }
}

// ---------------- recon: out = weighted . WrT^T + brsum ----------------
__global__ __launch_bounds__(256) void k_gemm_recon(
    const u16* __restrict__ weighted, const u16* __restrict__ WrT,
    const float* __restrict__ brsum, float* __restrict__ out)
{
    __shared__ u16 As[128 * 32], Bs[128 * 32];
    const int mt = blockIdx.y * 128, nt = blockIdx.x * 128;
    f32x4 acc[4][4];
    #pragma unroll
    for (int m = 0; m < 4; ++m)
        #pragma unroll
        for (int n = 0; n < 4; ++n) acc[m][n] = (f32x4){0.f, 0.f, 0.f, 0.f};
    gemm128_core(weighted + (size_t)mt * 1024, WrT + (size_t)nt * 1024,
                 1024, 1024, 1024, As, Bs, acc);
    const int l = threadIdx.x & 63, wv = threadIdx.x >> 6;
    const int wm = wv >> 1, wn = wv & 1;
    #pragma unroll
    for (int m = 0; m < 4; ++m)
        #pragma unroll
        for (int n = 0; n < 4; ++n)
            #pragma unroll
            for (int q = 0; q < 4; ++q) {
                const int row = mt + wm * 64 + m * 16 + (l >> 4) * 4 + q;
                const int col = nt + wn * 64 + n * 16 + (l & 15);
                out[(size_t)row * 1024 + col] = acc[m][n][q] + brsum[col];
            }
}

extern "C" void kernel_launch(void* const* d_in, const int* in_sizes, int n_in,
                              void* d_out, int out_size, void* d_ws, size_t ws_size,
                              hipStream_t stream) {
    const float* hx = (const float*)d_in[0];
    const float* ha = (const float*)d_in[1];
    const float* Wp = (const float*)d_in[2];
    const float* bp = (const float*)d_in[3];
    const float* Wr = (const float*)d_in[4];
    const float* br = (const float*)d_in[5];
    float* out = (float*)d_out;

    // Workspace map (117 MiB peak, <= 128 MiB):
    //  [0,16)  hxb (dead after proj) -> weighted (after sim/weighted phases)
    //  [16,32) hab (dead after proj)
    //  [32,34) WpT  [34,36) WrT  [36,+4K) brsum  [36M+256K,+128K) inv_na
    //  [37,53) xnb   [53,69) araw   [69,85) arawT   [85,117) w_half (32 MiB)
    char* W = (char*)d_ws;
    u16* hxb      = (u16*)(W);
    u16* hab      = (u16*)(W + (16ull << 20));
    u16* WpT      = (u16*)(W + (32ull << 20));
    u16* WrT      = (u16*)(W + (34ull << 20));
    float* brsum  = (float*)(W + (36ull << 20));
    float* inv_na = (float*)(W + (36ull << 20) + (256ull << 10));
    u16* xnb      = (u16*)(W + (37ull << 20));
    u16* araw     = (u16*)(W + (53ull << 20));
    u16* arawT    = (u16*)(W + (69ull << 20));
    u16* whalf    = (u16*)(W + (85ull << 20));
    u16* weighted = (u16*)(W);   // alias hxb

    // 1) casts + weight transposes + bias sum
    k_cast8<<<dim3(R_ * H_ / 8 / 256), dim3(256), 0, stream>>>(hx, hxb, R_ * H_ / 8);
    k_cast8<<<dim3(R_ * H_ / 8 / 256), dim3(256), 0, stream>>>(ha, hab, R_ * H_ / 8);
    k_tc_wp<<<dim3(16, 4, 4), dim3(256), 0, stream>>>(Wp, WpT);
    k_tc_wr<<<dim3(16, 16), dim3(256), 0, stream>>>(Wr, WrT);
    k_brsum<<<dim3(4), dim3(256), 0, stream>>>(br, brsum);

    // 2) fused projection + norm: xnb (normalized), araw (raw), inv_na
    k_proj_norm<<<dim3(4, 64, 2), dim3(512), 0, stream>>>(hxb, hab, WpT, bp, xnb, araw, inv_na);

    // 3) transpose araw -> arawT [(s,b)][d][j]
    k_tc_araw<<<dim3(16, 4, 32), dim3(256), 0, stream>>>(araw, arawT);

    // 4) sim+softmax -> w_half; weighted GEMM, ping-pong over i-halves
    for (int half = 0; half < 2; ++half) {
        k_sim_v2<<<dim3(8, 4, 8), dim3(512), 0, stream>>>(xnb, araw, inv_na, whalf, half);
        k_gemm_weighted<<<dim3(2, 4, 32), dim3(256), 0, stream>>>(whalf, arawT, weighted, half);
    }

    // 5) reconstruct + bias
    k_gemm_recon<<<dim3(8, 64), dim3(256), 0, stream>>>(weighted, WrT, brsum, out);
}

// Round 5
// 197.549 us; speedup vs baseline: 10.1110x; 1.0151x over previous
//
#include <hip/hip_runtime.h>
#include <hip/hip_bf16.h>

#define S_ 4
#define H_ 1024
#define D_ 256
#define B_ 8
#define N_ 1024
#define R_ (B_*N_)   /* 8192 */
#define EPS_ 1e-8f

typedef float f32x4 __attribute__((ext_vector_type(4)));
typedef short bf16x8 __attribute__((ext_vector_type(8)));
typedef unsigned short u16;

__device__ __forceinline__ u16 f2b(float f) {
    union { __bf16 h; u16 u; } cv; cv.h = (__bf16)f; return cv.u;
}

__device__ __forceinline__ void gload16(const void* g, void* l) {
    __builtin_amdgcn_global_load_lds((const __attribute__((address_space(1))) void*)g,
                                     (__attribute__((address_space(3))) void*)l, 16, 0, 0);
}

// ---------------- prep: fp32 -> bf16 cast, both inputs in one launch ----------------
__global__ __launch_bounds__(256) void k_cast8_2(const float* __restrict__ hx,
                                                 const float* __restrict__ ha,
                                                 u16* __restrict__ hxb, u16* __restrict__ hab,
                                                 int n8) {
    int i = blockIdx.x * 256 + threadIdx.x;
    const float* src; u16* dst;
    if (i < n8) { src = hx; dst = hxb; } else { src = ha; dst = hab; i -= n8; }
    const float4 v0 = ((const float4*)src)[2 * i];
    const float4 v1 = ((const float4*)src)[2 * i + 1];
    union { u16 u[8]; uint4 v; } o;
    o.u[0] = f2b(v0.x); o.u[1] = f2b(v0.y); o.u[2] = f2b(v0.z); o.u[3] = f2b(v0.w);
    o.u[4] = f2b(v1.x); o.u[5] = f2b(v1.y); o.u[6] = f2b(v1.z); o.u[7] = f2b(v1.w);
    ((uint4*)dst)[i] = o.v;
}

// ---------------- prep: 64x64 fp32 transpose + cast ----------------
__device__ __forceinline__ void tc64(const float* __restrict__ src, int lds_,
                                     u16* __restrict__ dst, int ldd) {
    __shared__ float t[64][65];
    const int tid = threadIdx.x;
    const int rr = tid >> 4;
    const int cc = (tid & 15) * 4;
    #pragma unroll
    for (int p = 0; p < 4; ++p) {
        const int r = rr + p * 16;
        const float4 v = *(const float4*)(src + (size_t)r * lds_ + cc);
        t[r][cc] = v.x; t[r][cc + 1] = v.y; t[r][cc + 2] = v.z; t[r][cc + 3] = v.w;
    }
    __syncthreads();
    #pragma unroll
    for (int p = 0; p < 4; ++p) {
        const int c = rr + p * 16;
        union { u16 u[4]; uint2 v; } o;
        o.u[0] = f2b(t[cc + 0][c]); o.u[1] = f2b(t[cc + 1][c]);
        o.u[2] = f2b(t[cc + 2][c]); o.u[3] = f2b(t[cc + 3][c]);
        *(uint2*)(dst + (size_t)c * ldd + cc) = o.v;
    }
}

__global__ __launch_bounds__(256) void k_tc_wp(const float* __restrict__ Wp, u16* __restrict__ WpT) {
    const int s = blockIdx.z;
    const int r0 = blockIdx.x * 64;   // h
    const int c0 = blockIdx.y * 64;   // d
    tc64(Wp + (size_t)s * H_ * D_ + (size_t)r0 * D_ + c0, D_,
         WpT + (size_t)s * D_ * H_ + (size_t)c0 * H_ + r0, H_);
}

__global__ __launch_bounds__(256) void k_tc_wr(const float* __restrict__ Wr, u16* __restrict__ WrT) {
    const int r0 = blockIdx.y * 64;   // sd
    const int c0 = blockIdx.x * 64;   // h
    tc64(Wr + (size_t)r0 * H_ + c0, H_,
         WrT + (size_t)c0 * H_ + r0, H_);
}

__global__ __launch_bounds__(256) void k_brsum(const float* __restrict__ br, float* __restrict__ bs) {
    const int h = blockIdx.x * 256 + threadIdx.x;
    if (h < H_) bs[h] = br[h] + br[H_ + h] + br[2 * H_ + h] + br[3 * H_ + h];
}

// ---------------- bf16 64x64 transpose: araw [r][s*256+d] -> arawT [(s,b)][d][j] ----------------
__global__ __launch_bounds__(256) void k_tc_araw(const u16* __restrict__ src, u16* __restrict__ dst) {
    const int sb = blockIdx.z, s = sb >> 3, b = sb & 7;
    const int j0 = blockIdx.x * 64, d0 = blockIdx.y * 64;
    __shared__ u16 tile[64][68];
    const int t = threadIdx.x;
    const int r = t >> 4, c4 = (t & 15) * 4;
    #pragma unroll
    for (int p = 0; p < 4; ++p) {
        const int row = p * 16 + r;
        *(uint2*)&tile[row][c4] =
            *(const uint2*)(src + (size_t)(b * N_ + j0 + row) * 1024 + s * 256 + d0 + c4);
    }
    __syncthreads();
    #pragma unroll
    for (int p = 0; p < 4; ++p) {
        const int orow = p * 16 + r;      // d-index
        union { u16 u[4]; uint2 v; } o;
        o.u[0] = tile[c4 + 0][orow]; o.u[1] = tile[c4 + 1][orow];
        o.u[2] = tile[c4 + 2][orow]; o.u[3] = tile[c4 + 3][orow];
        *(uint2*)(dst + ((size_t)sb << 18) + (size_t)(d0 + orow) * 1024 + j0 + c4) = o.v;
    }
}

// ============ reusable dbuf BK=64 GEMM core: C = A(TMxK) . B^T(TNxK) ============
// WROWS x WCOLS waves; wave tile (MFR*16) x (NFR*16). XOR-swizzled staging (rule #21:
// inverse-swizzled global source + linear LDS dest + swizzled LDS read).
template<int WROWS, int WCOLS, int MFR, int NFR>
__device__ __forceinline__ void gemm_dbuf(
    const u16* __restrict__ Ag, const u16* __restrict__ Bg,
    int lda, int ldb, int K, u16* SA, u16* SB, f32x4 (&acc)[MFR][NFR])
{
    constexpr int NT = WROWS * WCOLS * 64;
    constexpr int TM = WROWS * MFR * 16;
    constexpr int TN = WCOLS * NFR * 16;
    constexpr int CA = TM * 8 / NT;       // 16B chunks per thread for A
    constexpr int CB = TN * 8 / NT;
    constexpr int L  = CA + CB;           // vmem instrs per STAGE per thread
    const int tid = threadIdx.x, l = tid & 63, wv = tid >> 6;
    const int wm = wv / WCOLS, wn = wv % WCOLS;
    const int nsteps = K / 64;

    auto STAGE = [&](int buf, int k0) {
        #pragma unroll
        for (int i = 0; i < CA; ++i) {
            const int ci = i * NT + tid;
            const int row = ci >> 3, c = ci & 7, cs = c ^ (row & 7);
            gload16(Ag + (size_t)row * lda + k0 + cs * 8, SA + buf * TM * 64 + ci * 8);
        }
        #pragma unroll
        for (int i = 0; i < CB; ++i) {
            const int ci = i * NT + tid;
            const int row = ci >> 3, c = ci & 7, cs = c ^ (row & 7);
            gload16(Bg + (size_t)row * ldb + k0 + cs * 8, SB + buf * TN * 64 + ci * 8);
        }
    };

    STAGE(0, 0);
    for (int t = 0; t < nsteps; ++t) {
        const int cur = t & 1;
        if (t < nsteps - 1) {
            STAGE(cur ^ 1, (t + 1) * 64);
            if constexpr (L == 3)      asm volatile("s_waitcnt vmcnt(3)" ::: "memory");
            else if constexpr (L == 6) asm volatile("s_waitcnt vmcnt(6)" ::: "memory");
            else if constexpr (L == 8) asm volatile("s_waitcnt vmcnt(8)" ::: "memory");
            else                       asm volatile("s_waitcnt vmcnt(0)" ::: "memory");
        } else {
            asm volatile("s_waitcnt vmcnt(0)" ::: "memory");
        }
        __builtin_amdgcn_s_barrier();
        __builtin_amdgcn_sched_barrier(0);
        bf16x8 af[2][MFR], bq[2][NFR];
        #pragma unroll
        for (int kc = 0; kc < 2; ++kc) {
            #pragma unroll
            for (int m = 0; m < MFR; ++m) {
                const int r = wm * MFR * 16 + m * 16 + (l & 15);
                const int c = (kc * 4 + (l >> 4)) ^ (r & 7);
                af[kc][m] = *(const bf16x8*)(SA + cur * TM * 64 + r * 64 + c * 8);
            }
            #pragma unroll
            for (int n = 0; n < NFR; ++n) {
                const int r = wn * NFR * 16 + n * 16 + (l & 15);
                const int c = (kc * 4 + (l >> 4)) ^ (r & 7);
                bq[kc][n] = *(const bf16x8*)(SB + cur * TN * 64 + r * 64 + c * 8);
            }
        }
        asm volatile("s_waitcnt lgkmcnt(0)" ::: "memory");
        __builtin_amdgcn_s_barrier();
        __builtin_amdgcn_sched_barrier(0);
        #pragma unroll
        for (int kc = 0; kc < 2; ++kc)
            #pragma unroll
            for (int m = 0; m < MFR; ++m)
                #pragma unroll
                for (int n = 0; n < NFR; ++n)
                    acc[m][n] = __builtin_amdgcn_mfma_f32_16x16x32_bf16(af[kc][m], bq[kc][n], acc[m][n], 0, 0, 0);
    }
}

// ---------------- proj (fused norm), dbuf pipeline, 128x256 tile ----------------
__global__ __launch_bounds__(512, 2) void k_proj_norm(
    const u16* __restrict__ hxb, const u16* __restrict__ hab,
    const u16* __restrict__ WpT, const float* __restrict__ bp,
    u16* __restrict__ xnb, u16* __restrict__ araw, float* __restrict__ inv_na)
{
    __shared__ u16 SA[2 * 128 * 64];
    __shared__ u16 SB[2 * 256 * 64];
    __shared__ float normbuf[128][4];

    const int is_a = blockIdx.z;
    const int s  = blockIdx.x;            // n-tile == subspace (256 cols)
    const int rt = blockIdx.y * 128;
    const int tid = threadIdx.x;
    const int l = tid & 63, wv = tid >> 6;
    const int wm = wv >> 2, wn = wv & 3;  // 2 x 4
    const u16* __restrict__ Ag = (is_a ? hab : hxb) + (size_t)rt * 1024;
    const u16* __restrict__ Bg = WpT + (size_t)(s * 256) * 1024;

    f32x4 acc[4][4];
    #pragma unroll
    for (int m = 0; m < 4; ++m)
        #pragma unroll
        for (int n = 0; n < 4; ++n) acc[m][n] = (f32x4){0.f, 0.f, 0.f, 0.f};

    gemm_dbuf<2, 4, 4, 4>(Ag, Bg, 1024, 1024, 1024, SA, SB, acc);

    // ---- epilogue: bias, row L2-norm over the 256-col subspace, write bf16 ----
    float bv[4];
    #pragma unroll
    for (int n = 0; n < 4; ++n) bv[n] = bp[s * 256 + wn * 64 + n * 16 + (l & 15)];
    #pragma unroll
    for (int m = 0; m < 4; ++m)
        #pragma unroll
        for (int n = 0; n < 4; ++n)
            #pragma unroll
            for (int q = 0; q < 4; ++q) acc[m][n][q] += bv[n];

    float ss[4][4];
    #pragma unroll
    for (int m = 0; m < 4; ++m)
        #pragma unroll
        for (int q = 0; q < 4; ++q) {
            float v = 0.f;
            #pragma unroll
            for (int n = 0; n < 4; ++n) v += acc[m][n][q] * acc[m][n][q];
            ss[m][q] = v;
        }
    #pragma unroll
    for (int off = 1; off <= 8; off <<= 1)
        #pragma unroll
        for (int m = 0; m < 4; ++m)
            #pragma unroll
            for (int q = 0; q < 4; ++q) ss[m][q] += __shfl_xor(ss[m][q], off, 64);
    if ((l & 15) == 0) {
        #pragma unroll
        for (int m = 0; m < 4; ++m)
            #pragma unroll
            for (int q = 0; q < 4; ++q)
                normbuf[wm * 64 + m * 16 + (l >> 4) * 4 + q][wn] = ss[m][q];
    }
    __syncthreads();
    float sc[4][4];
    #pragma unroll
    for (int m = 0; m < 4; ++m)
        #pragma unroll
        for (int q = 0; q < 4; ++q) {
            const int rl = wm * 64 + m * 16 + (l >> 4) * 4 + q;
            const float tot = normbuf[rl][0] + normbuf[rl][1] + normbuf[rl][2] + normbuf[rl][3];
            sc[m][q] = 1.0f / fmaxf(sqrtf(tot), EPS_);
        }
    if (!is_a) {
        #pragma unroll
        for (int m = 0; m < 4; ++m)
            #pragma unroll
            for (int n = 0; n < 4; ++n)
                #pragma unroll
                for (int q = 0; q < 4; ++q) {
                    const int rl = wm * 64 + m * 16 + (l >> 4) * 4 + q;
                    xnb[(size_t)(rt + rl) * 1024 + s * 256 + wn * 64 + n * 16 + (l & 15)] =
                        f2b(acc[m][n][q] * sc[m][q]);
                }
    } else {
        #pragma unroll
        for (int m = 0; m < 4; ++m)
            #pragma unroll
            for (int n = 0; n < 4; ++n)
                #pragma unroll
                for (int q = 0; q < 4; ++q) {
                    const int rl = wm * 64 + m * 16 + (l >> 4) * 4 + q;
                    araw[(size_t)(rt + rl) * 1024 + s * 256 + wn * 64 + n * 16 + (l & 15)] =
                        f2b(acc[m][n][q]);
                }
        if (wn == 0 && (l & 15) == 0) {
            #pragma unroll
            for (int m = 0; m < 4; ++m)
                #pragma unroll
                for (int q = 0; q < 4; ++q) {
                    const int rl = wm * 64 + m * 16 + (l >> 4) * 4 + q;
                    inv_na[s * R_ + rt + rl] = sc[m][q];
                }
        }
    }
}

// ---------------- sim v3: TM=64, dbuf, fused softmax(s) ----------------
__global__ __launch_bounds__(512, 2) void k_sim_v3(
    const u16* __restrict__ xnb, const u16* __restrict__ araw,
    const float* __restrict__ inv_na, u16* __restrict__ whalf, const int half)
{
    __shared__ u16 SmA[2 * 64 * 64];
    __shared__ u16 SmB[2 * 128 * 64];
    const int b   = blockIdx.z;
    const int itl = blockIdx.y * 64;             // local to half (0..448)
    const int it  = half * 512 + itl;
    const int jt  = blockIdx.x * 128;
    const int tid = threadIdx.x, l = tid & 63, wv = tid >> 6;  // 8 waves
    const int wi = wv >> 2, wj = wv & 3;         // 2 x 4 -> wave tile 32 x 32 (per s)
    const u16* __restrict__ Ag = xnb  + (size_t)(b * N_ + it) * 1024;
    const u16* __restrict__ Bg = araw + (size_t)(b * N_ + jt) * 1024;

    f32x4 acc[4][2][2];  // [s][m][n]
    #pragma unroll
    for (int s = 0; s < 4; ++s)
        #pragma unroll
        for (int m = 0; m < 2; ++m)
            #pragma unroll
            for (int n = 0; n < 2; ++n) acc[s][m][n] = (f32x4){0.f, 0.f, 0.f, 0.f};

    auto STAGE = [&](int buf, int t) {
        const int k0 = t * 64;
        {   // A: 64x64 -> 512 chunks, 1/thread
            const int ci = tid;
            const int row = ci >> 3, c = ci & 7, cs = c ^ (row & 7);
            gload16(Ag + (size_t)row * 1024 + k0 + cs * 8, SmA + buf * 4096 + ci * 8);
        }
        #pragma unroll
        for (int i = 0; i < 2; ++i) {   // B: 128x64 -> 1024 chunks, 2/thread
            const int ci = i * 512 + tid;
            const int row = ci >> 3, c = ci & 7, cs = c ^ (row & 7);
            gload16(Bg + (size_t)row * 1024 + k0 + cs * 8, SmB + buf * 8192 + ci * 8);
        }
    };

    STAGE(0, 0);
    #pragma unroll
    for (int s = 0; s < 4; ++s) {
        #pragma unroll
        for (int kk = 0; kk < 4; ++kk) {
            const int t = s * 4 + kk;
            const int cur = t & 1;
            if (t < 15) {
                STAGE(cur ^ 1, t + 1);
                asm volatile("s_waitcnt vmcnt(3)" ::: "memory");
            } else {
                asm volatile("s_waitcnt vmcnt(0)" ::: "memory");
            }
            __builtin_amdgcn_s_barrier();
            __builtin_amdgcn_sched_barrier(0);
            bf16x8 af[2][2], bq[2][2];
            #pragma unroll
            for (int kc = 0; kc < 2; ++kc) {
                #pragma unroll
                for (int m = 0; m < 2; ++m) {
                    const int r = wi * 32 + m * 16 + (l & 15);
                    const int c = (kc * 4 + (l >> 4)) ^ (r & 7);
                    af[kc][m] = *(const bf16x8*)(SmA + cur * 4096 + r * 64 + c * 8);
                }
                #pragma unroll
                for (int n = 0; n < 2; ++n) {
                    const int r = wj * 32 + n * 16 + (l & 15);
                    const int c = (kc * 4 + (l >> 4)) ^ (r & 7);
                    bq[kc][n] = *(const bf16x8*)(SmB + cur * 8192 + r * 64 + c * 8);
                }
            }
            asm volatile("s_waitcnt lgkmcnt(0)" ::: "memory");
            __builtin_amdgcn_s_barrier();
            __builtin_amdgcn_sched_barrier(0);
            #pragma unroll
            for (int kc = 0; kc < 2; ++kc)
                #pragma unroll
                for (int m = 0; m < 2; ++m)
                    #pragma unroll
                    for (int n = 0; n < 2; ++n)
                        acc[s][m][n] = __builtin_amdgcn_mfma_f32_16x16x32_bf16(
                            af[kc][m], bq[kc][n], acc[s][m][n], 0, 0, 0);
        }
    }

    // ---- epilogue: scale by inv_na[j], softmax over s, write w (bf16) ----
    #pragma unroll
    for (int n = 0; n < 2; ++n) {
        const int jg = jt + wj * 32 + n * 16 + (l & 15);
        float inv[4];
        #pragma unroll
        for (int s = 0; s < 4; ++s) inv[s] = inv_na[s * R_ + b * N_ + jg];
        #pragma unroll
        for (int m = 0; m < 2; ++m)
            #pragma unroll
            for (int q = 0; q < 4; ++q) {
                const int il = itl + wi * 32 + m * 16 + (l >> 4) * 4 + q;
                float e[4]; float sum = 0.f;
                #pragma unroll
                for (int s = 0; s < 4; ++s) { e[s] = __expf(acc[s][m][n][q] * inv[s]); sum += e[s]; }
                const float rs = 1.0f / sum;
                #pragma unroll
                for (int s = 0; s < 4; ++s)
                    whalf[((size_t)(s * B_ + b) << 19) + (size_t)il * 1024 + jg] = f2b(e[s] * rs);
            }
    }
}

// ---------------- weighted = w_half . arawT^T (per s,b), 64x128 tile ----------------
__global__ __launch_bounds__(256, 2) void k_gemm_weighted(
    const u16* __restrict__ whalf, const u16* __restrict__ arawT,
    u16* __restrict__ weighted, const int half)
{
    __shared__ u16 SA[2 * 64 * 64];
    __shared__ u16 SB[2 * 128 * 64];
    const int sb = blockIdx.z, s = sb >> 3, b = sb & 7;
    const int mt = blockIdx.y * 64, nt = blockIdx.x * 128;
    f32x4 acc[2][4];
    #pragma unroll
    for (int m = 0; m < 2; ++m)
        #pragma unroll
        for (int n = 0; n < 4; ++n) acc[m][n] = (f32x4){0.f, 0.f, 0.f, 0.f};
    gemm_dbuf<2, 2, 2, 4>(whalf + ((size_t)sb << 19) + (size_t)mt * 1024,
                          arawT + ((size_t)sb << 18) + (size_t)nt * 1024,
                          1024, 1024, 1024, SA, SB, acc);
    const int l = threadIdx.x & 63, wv = threadIdx.x >> 6;
    const int wm = wv >> 1, wn = wv & 1;
    #pragma unroll
    for (int m = 0; m < 2; ++m)
        #pragma unroll
        for (int n = 0; n < 4; ++n)
            #pragma unroll
            for (int q = 0; q < 4; ++q) {
                const int i = half * 512 + mt + wm * 32 + m * 16 + (l >> 4) * 4 + q;
                const int d = nt + wn * 64 + n * 16 + (l & 15);
                weighted[(size_t)(b * N_ + i) * 1024 + s * 256 + d] = f2b(acc[m][n][q]);
            }
}

// ---------------- recon: out = weighted . WrT^T + brsum, 128x128 tile ----------------
__global__ __launch_bounds__(256, 2) void k_gemm_recon(
    const u16* __restrict__ weighted, const u16* __restrict__ WrT,
    const float* __restrict__ brsum, float* __restrict__ out)
{
    __shared__ u16 SA[2 * 128 * 64];
    __shared__ u16 SB[2 * 128 * 64];
    const int mt = blockIdx.y * 128, nt = blockIdx.x * 128;
    f32x4 acc[4][4];
    #pragma unroll
    for (int m = 0; m < 4; ++m)
        #pragma unroll
        for (int n = 0; n < 4; ++n) acc[m][n] = (f32x4){0.f, 0.f, 0.f, 0.f};
    gemm_dbuf<2, 2, 4, 4>(weighted + (size_t)mt * 1024, WrT + (size_t)nt * 1024,
                          1024, 1024, 1024, SA, SB, acc);
    const int l = threadIdx.x & 63, wv = threadIdx.x >> 6;
    const int wm = wv >> 1, wn = wv & 1;
    #pragma unroll
    for (int m = 0; m < 4; ++m)
        #pragma unroll
        for (int n = 0; n < 4; ++n)
            #pragma unroll
            for (int q = 0; q < 4; ++q) {
                const int row = mt + wm * 64 + m * 16 + (l >> 4) * 4 + q;
                const int col = nt + wn * 64 + n * 16 + (l & 15);
                out[(size_t)row * 1024 + col] = acc[m][n][q] + brsum[col];
            }
}

extern "C" void kernel_launch(void* const* d_in, const int* in_sizes, int n_in,
                              void* d_out, int out_size, void* d_ws, size_t ws_size,
                              hipStream_t stream) {
    const float* hx = (const float*)d_in[0];
    const float* ha = (const float*)d_in[1];
    const float* Wp = (const float*)d_in[2];
    const float* bp = (const float*)d_in[3];
    const float* Wr = (const float*)d_in[4];
    const float* br = (const float*)d_in[5];
    float* out = (float*)d_out;

    // Workspace map (117 MiB peak, <= 128 MiB):
    //  [0,16)  hxb (dead after proj) -> weighted
    //  [16,32) hab (dead after proj)
    //  [32,34) WpT  [34,36) WrT  [36,+4K) brsum  [36M+256K,+128K) inv_na
    //  [37,53) xnb   [53,69) araw   [69,85) arawT   [85,117) w_half (32 MiB)
    char* W = (char*)d_ws;
    u16* hxb      = (u16*)(W);
    u16* hab      = (u16*)(W + (16ull << 20));
    u16* WpT      = (u16*)(W + (32ull << 20));
    u16* WrT      = (u16*)(W + (34ull << 20));
    float* brsum  = (float*)(W + (36ull << 20));
    float* inv_na = (float*)(W + (36ull << 20) + (256ull << 10));
    u16* xnb      = (u16*)(W + (37ull << 20));
    u16* araw     = (u16*)(W + (53ull << 20));
    u16* arawT    = (u16*)(W + (69ull << 20));
    u16* whalf    = (u16*)(W + (85ull << 20));
    u16* weighted = (u16*)(W);   // alias hxb

    // 1) casts + weight transposes + bias sum
    k_cast8_2<<<dim3(2 * R_ * H_ / 8 / 256), dim3(256), 0, stream>>>(hx, ha, hxb, hab, R_ * H_ / 8);
    k_tc_wp<<<dim3(16, 4, 4), dim3(256), 0, stream>>>(Wp, WpT);
    k_tc_wr<<<dim3(16, 16), dim3(256), 0, stream>>>(Wr, WrT);
    k_brsum<<<dim3(4), dim3(256), 0, stream>>>(br, brsum);

    // 2) fused projection + norm (dbuf pipeline)
    k_proj_norm<<<dim3(4, 64, 2), dim3(512), 0, stream>>>(hxb, hab, WpT, bp, xnb, araw, inv_na);

    // 3) transpose araw -> arawT [(s,b)][d][j]
    k_tc_araw<<<dim3(16, 4, 32), dim3(256), 0, stream>>>(araw, arawT);

    // 4) sim+softmax -> w_half; weighted GEMM, ping-pong over i-halves
    for (int half = 0; half < 2; ++half) {
        k_sim_v3<<<dim3(8, 8, 8), dim3(512), 0, stream>>>(xnb, araw, inv_na, whalf, half);
        // FIX(R4): grid.x must cover D=256 with TN=128 -> 2 blocks, not 1.
        k_gemm_weighted<<<dim3(2, 8, 32), dim3(256), 0, stream>>>(whalf, arawT, weighted, half);
    }

    // 5) reconstruct + bias
    k_gemm_recon<<<dim3(8, 64), dim3(256), 0, stream>>>(weighted, WrT, brsum, out);
}

// Round 6
// 186.174 us; speedup vs baseline: 10.7288x; 1.0611x over previous
//
#include <hip/hip_runtime.h>
#include <hip/hip_bf16.h>

#define S_ 4
#define H_ 1024
#define D_ 256
#define B_ 8
#define N_ 1024
#define R_ (B_*N_)   /* 8192 */
#define EPS_ 1e-8f

typedef float f32x4 __attribute__((ext_vector_type(4)));
typedef short bf16x8 __attribute__((ext_vector_type(8)));
typedef unsigned short u16;

__device__ __forceinline__ u16 f2b(float f) {
    union { __bf16 h; u16 u; } cv; cv.h = (__bf16)f; return cv.u;
}

__device__ __forceinline__ void gload16(const void* g, void* l) {
    __builtin_amdgcn_global_load_lds((const __attribute__((address_space(1))) void*)g,
                                     (__attribute__((address_space(3))) void*)l, 16, 0, 0);
}

// ---------------- prep: fp32 -> bf16 cast, both inputs in one launch ----------------
__global__ __launch_bounds__(256) void k_cast8_2(const float* __restrict__ hx,
                                                 const float* __restrict__ ha,
                                                 u16* __restrict__ hxb, u16* __restrict__ hab,
                                                 int n8) {
    int i = blockIdx.x * 256 + threadIdx.x;
    const float* src; u16* dst;
    if (i < n8) { src = hx; dst = hxb; } else { src = ha; dst = hab; i -= n8; }
    const float4 v0 = ((const float4*)src)[2 * i];
    const float4 v1 = ((const float4*)src)[2 * i + 1];
    union { u16 u[8]; uint4 v; } o;
    o.u[0] = f2b(v0.x); o.u[1] = f2b(v0.y); o.u[2] = f2b(v0.z); o.u[3] = f2b(v0.w);
    o.u[4] = f2b(v1.x); o.u[5] = f2b(v1.y); o.u[6] = f2b(v1.z); o.u[7] = f2b(v1.w);
    ((uint4*)dst)[i] = o.v;
}

// ---------------- prep: 64x64 fp32 transpose + cast ----------------
__device__ __forceinline__ void tc64(const float* __restrict__ src, int lds_,
                                     u16* __restrict__ dst, int ldd) {
    __shared__ float t[64][65];
    const int tid = threadIdx.x;
    const int rr = tid >> 4;
    const int cc = (tid & 15) * 4;
    #pragma unroll
    for (int p = 0; p < 4; ++p) {
        const int r = rr + p * 16;
        const float4 v = *(const float4*)(src + (size_t)r * lds_ + cc);
        t[r][cc] = v.x; t[r][cc + 1] = v.y; t[r][cc + 2] = v.z; t[r][cc + 3] = v.w;
    }
    __syncthreads();
    #pragma unroll
    for (int p = 0; p < 4; ++p) {
        const int c = rr + p * 16;
        union { u16 u[4]; uint2 v; } o;
        o.u[0] = f2b(t[cc + 0][c]); o.u[1] = f2b(t[cc + 1][c]);
        o.u[2] = f2b(t[cc + 2][c]); o.u[3] = f2b(t[cc + 3][c]);
        *(uint2*)(dst + (size_t)c * ldd + cc) = o.v;
    }
}

__global__ __launch_bounds__(256) void k_tc_wp(const float* __restrict__ Wp, u16* __restrict__ WpT) {
    const int s = blockIdx.z;
    const int r0 = blockIdx.x * 64;   // h
    const int c0 = blockIdx.y * 64;   // d
    tc64(Wp + (size_t)s * H_ * D_ + (size_t)r0 * D_ + c0, D_,
         WpT + (size_t)s * D_ * H_ + (size_t)c0 * H_ + r0, H_);
}

__global__ __launch_bounds__(256) void k_tc_wr(const float* __restrict__ Wr, u16* __restrict__ WrT) {
    const int r0 = blockIdx.y * 64;   // sd
    const int c0 = blockIdx.x * 64;   // h
    tc64(Wr + (size_t)r0 * H_ + c0, H_,
         WrT + (size_t)c0 * H_ + r0, H_);
}

__global__ __launch_bounds__(256) void k_brsum(const float* __restrict__ br, float* __restrict__ bs) {
    const int h = blockIdx.x * 256 + threadIdx.x;
    if (h < H_) bs[h] = br[h] + br[H_ + h] + br[2 * H_ + h] + br[3 * H_ + h];
}

// ---------------- bf16 64x64 transpose: araw [r][s*256+d] -> arawT [(s,b)][d][j] ----------------
__global__ __launch_bounds__(256) void k_tc_araw(const u16* __restrict__ src, u16* __restrict__ dst) {
    const int sb = blockIdx.z, s = sb >> 3, b = sb & 7;
    const int j0 = blockIdx.x * 64, d0 = blockIdx.y * 64;
    __shared__ u16 tile[64][68];
    const int t = threadIdx.x;
    const int r = t >> 4, c4 = (t & 15) * 4;
    #pragma unroll
    for (int p = 0; p < 4; ++p) {
        const int row = p * 16 + r;
        *(uint2*)&tile[row][c4] =
            *(const uint2*)(src + (size_t)(b * N_ + j0 + row) * 1024 + s * 256 + d0 + c4);
    }
    __syncthreads();
    #pragma unroll
    for (int p = 0; p < 4; ++p) {
        const int orow = p * 16 + r;      // d-index
        union { u16 u[4]; uint2 v; } o;
        o.u[0] = tile[c4 + 0][orow]; o.u[1] = tile[c4 + 1][orow];
        o.u[2] = tile[c4 + 2][orow]; o.u[3] = tile[c4 + 3][orow];
        *(uint2*)(dst + ((size_t)sb << 18) + (size_t)(d0 + orow) * 1024 + j0 + c4) = o.v;
    }
}

// ============ reusable dbuf BK=64 GEMM core: C = A(TMxK) . B^T(TNxK) ============
template<int WROWS, int WCOLS, int MFR, int NFR>
__device__ __forceinline__ void gemm_dbuf(
    const u16* __restrict__ Ag, const u16* __restrict__ Bg,
    int lda, int ldb, int K, u16* SA, u16* SB, f32x4 (&acc)[MFR][NFR])
{
    constexpr int NT = WROWS * WCOLS * 64;
    constexpr int TM = WROWS * MFR * 16;
    constexpr int TN = WCOLS * NFR * 16;
    constexpr int CA = TM * 8 / NT;       // 16B chunks per thread for A
    constexpr int CB = TN * 8 / NT;
    constexpr int L  = CA + CB;           // vmem instrs per STAGE per thread
    const int tid = threadIdx.x, l = tid & 63, wv = tid >> 6;
    const int wm = wv / WCOLS, wn = wv % WCOLS;
    const int nsteps = K / 64;

    auto STAGE = [&](int buf, int k0) {
        #pragma unroll
        for (int i = 0; i < CA; ++i) {
            const int ci = i * NT + tid;
            const int row = ci >> 3, c = ci & 7, cs = c ^ (row & 7);
            gload16(Ag + (size_t)row * lda + k0 + cs * 8, SA + buf * TM * 64 + ci * 8);
        }
        #pragma unroll
        for (int i = 0; i < CB; ++i) {
            const int ci = i * NT + tid;
            const int row = ci >> 3, c = ci & 7, cs = c ^ (row & 7);
            gload16(Bg + (size_t)row * ldb + k0 + cs * 8, SB + buf * TN * 64 + ci * 8);
        }
    };

    STAGE(0, 0);
    for (int t = 0; t < nsteps; ++t) {
        const int cur = t & 1;
        if (t < nsteps - 1) {
            STAGE(cur ^ 1, (t + 1) * 64);
            if constexpr (L == 3)      asm volatile("s_waitcnt vmcnt(3)" ::: "memory");
            else if constexpr (L == 6) asm volatile("s_waitcnt vmcnt(6)" ::: "memory");
            else if constexpr (L == 8) asm volatile("s_waitcnt vmcnt(8)" ::: "memory");
            else                       asm volatile("s_waitcnt vmcnt(0)" ::: "memory");
        } else {
            asm volatile("s_waitcnt vmcnt(0)" ::: "memory");
        }
        __builtin_amdgcn_s_barrier();
        __builtin_amdgcn_sched_barrier(0);
        bf16x8 af[2][MFR], bq[2][NFR];
        #pragma unroll
        for (int kc = 0; kc < 2; ++kc) {
            #pragma unroll
            for (int m = 0; m < MFR; ++m) {
                const int r = wm * MFR * 16 + m * 16 + (l & 15);
                const int c = (kc * 4 + (l >> 4)) ^ (r & 7);
                af[kc][m] = *(const bf16x8*)(SA + cur * TM * 64 + r * 64 + c * 8);
            }
            #pragma unroll
            for (int n = 0; n < NFR; ++n) {
                const int r = wn * NFR * 16 + n * 16 + (l & 15);
                const int c = (kc * 4 + (l >> 4)) ^ (r & 7);
                bq[kc][n] = *(const bf16x8*)(SB + cur * TN * 64 + r * 64 + c * 8);
            }
        }
        asm volatile("s_waitcnt lgkmcnt(0)" ::: "memory");
        __builtin_amdgcn_s_barrier();
        __builtin_amdgcn_sched_barrier(0);
        #pragma unroll
        for (int kc = 0; kc < 2; ++kc)
            #pragma unroll
            for (int m = 0; m < MFR; ++m)
                #pragma unroll
                for (int n = 0; n < NFR; ++n)
                    acc[m][n] = __builtin_amdgcn_mfma_f32_16x16x32_bf16(af[kc][m], bq[kc][n], acc[m][n], 0, 0, 0);
    }
}

// ---------------- proj (fused norm) v3: 128x256 tile, BK=32 dbuf (50KB LDS -> 2 blk/CU) ----------------
__global__ __launch_bounds__(512, 4) void k_proj_norm(
    const u16* __restrict__ hxb, const u16* __restrict__ hab,
    const u16* __restrict__ WpT, const float* __restrict__ bp,
    u16* __restrict__ xnb, u16* __restrict__ araw, float* __restrict__ inv_na)
{
    __shared__ u16 SA[2 * 128 * 32];   // 16 KB
    __shared__ u16 SB[2 * 256 * 32];   // 32 KB
    __shared__ float normbuf[128][4];  //  2 KB

    const int is_a = blockIdx.z;
    const int s  = blockIdx.y;            // subspace (256-col n-tile)
    const int rt = blockIdx.x * 128;      // rt fastest -> blocks sharing inputs on same XCD
    const int tid = threadIdx.x;
    const int l = tid & 63, wv = tid >> 6;
    const int wm = wv >> 2, wn = wv & 3;  // 2 x 4, wave tile 64x64
    const u16* __restrict__ Ag = (is_a ? hab : hxb) + (size_t)rt * 1024;
    const u16* __restrict__ Bg = WpT + (size_t)(s * 256) * 1024;

    f32x4 acc[4][4];
    #pragma unroll
    for (int m = 0; m < 4; ++m)
        #pragma unroll
        for (int n = 0; n < 4; ++n) acc[m][n] = (f32x4){0.f, 0.f, 0.f, 0.f};

    // BK=32 double-buffered pipeline, 3 loads/thread per stage
    auto STAGE = [&](int buf, int k0) {
        {   // A: 128x32 = 512 chunks, 1/thread
            const int ci = tid;
            const int row = ci >> 2, c = ci & 3, cs = c ^ (row & 3);
            gload16(Ag + (size_t)row * 1024 + k0 + cs * 8, SA + buf * 4096 + ci * 8);
        }
        #pragma unroll
        for (int i = 0; i < 2; ++i) {   // B: 256x32 = 1024 chunks, 2/thread
            const int ci = i * 512 + tid;
            const int row = ci >> 2, c = ci & 3, cs = c ^ (row & 3);
            gload16(Bg + (size_t)row * 1024 + k0 + cs * 8, SB + buf * 8192 + ci * 8);
        }
    };

    STAGE(0, 0);
    for (int t = 0; t < 32; ++t) {
        const int cur = t & 1;
        if (t < 31) {
            STAGE(cur ^ 1, (t + 1) * 32);
            asm volatile("s_waitcnt vmcnt(3)" ::: "memory");
        } else {
            asm volatile("s_waitcnt vmcnt(0)" ::: "memory");
        }
        __builtin_amdgcn_s_barrier();
        __builtin_amdgcn_sched_barrier(0);
        bf16x8 af[4], bq[4];
        #pragma unroll
        for (int m = 0; m < 4; ++m) {
            const int r = wm * 64 + m * 16 + (l & 15);
            const int c = (l >> 4) ^ (r & 3);
            af[m] = *(const bf16x8*)(SA + cur * 4096 + r * 32 + c * 8);
        }
        #pragma unroll
        for (int n = 0; n < 4; ++n) {
            const int r = wn * 64 + n * 16 + (l & 15);
            const int c = (l >> 4) ^ (r & 3);
            bq[n] = *(const bf16x8*)(SB + cur * 8192 + r * 32 + c * 8);
        }
        asm volatile("s_waitcnt lgkmcnt(0)" ::: "memory");
        __builtin_amdgcn_s_barrier();
        __builtin_amdgcn_sched_barrier(0);
        #pragma unroll
        for (int m = 0; m < 4; ++m)
            #pragma unroll
            for (int n = 0; n < 4; ++n)
                acc[m][n] = __builtin_amdgcn_mfma_f32_16x16x32_bf16(af[m], bq[n], acc[m][n], 0, 0, 0);
    }

    // ---- epilogue: bias, row L2-norm over the 256-col subspace, write bf16 ----
    float bv[4];
    #pragma unroll
    for (int n = 0; n < 4; ++n) bv[n] = bp[s * 256 + wn * 64 + n * 16 + (l & 15)];
    #pragma unroll
    for (int m = 0; m < 4; ++m)
        #pragma unroll
        for (int n = 0; n < 4; ++n)
            #pragma unroll
            for (int q = 0; q < 4; ++q) acc[m][n][q] += bv[n];

    float ss[4][4];
    #pragma unroll
    for (int m = 0; m < 4; ++m)
        #pragma unroll
        for (int q = 0; q < 4; ++q) {
            float v = 0.f;
            #pragma unroll
            for (int n = 0; n < 4; ++n) v += acc[m][n][q] * acc[m][n][q];
            ss[m][q] = v;
        }
    #pragma unroll
    for (int off = 1; off <= 8; off <<= 1)
        #pragma unroll
        for (int m = 0; m < 4; ++m)
            #pragma unroll
            for (int q = 0; q < 4; ++q) ss[m][q] += __shfl_xor(ss[m][q], off, 64);
    if ((l & 15) == 0) {
        #pragma unroll
        for (int m = 0; m < 4; ++m)
            #pragma unroll
            for (int q = 0; q < 4; ++q)
                normbuf[wm * 64 + m * 16 + (l >> 4) * 4 + q][wn] = ss[m][q];
    }
    __syncthreads();
    float sc[4][4];
    #pragma unroll
    for (int m = 0; m < 4; ++m)
        #pragma unroll
        for (int q = 0; q < 4; ++q) {
            const int rl = wm * 64 + m * 16 + (l >> 4) * 4 + q;
            const float tot = normbuf[rl][0] + normbuf[rl][1] + normbuf[rl][2] + normbuf[rl][3];
            sc[m][q] = 1.0f / fmaxf(sqrtf(tot), EPS_);
        }
    if (!is_a) {
        #pragma unroll
        for (int m = 0; m < 4; ++m)
            #pragma unroll
            for (int n = 0; n < 4; ++n)
                #pragma unroll
                for (int q = 0; q < 4; ++q) {
                    const int rl = wm * 64 + m * 16 + (l >> 4) * 4 + q;
                    xnb[(size_t)(rt + rl) * 1024 + s * 256 + wn * 64 + n * 16 + (l & 15)] =
                        f2b(acc[m][n][q] * sc[m][q]);
                }
    } else {
        #pragma unroll
        for (int m = 0; m < 4; ++m)
            #pragma unroll
            for (int n = 0; n < 4; ++n)
                #pragma unroll
                for (int q = 0; q < 4; ++q) {
                    const int rl = wm * 64 + m * 16 + (l >> 4) * 4 + q;
                    araw[(size_t)(rt + rl) * 1024 + s * 256 + wn * 64 + n * 16 + (l & 15)] =
                        f2b(acc[m][n][q]);
                }
        if (wn == 0 && (l & 15) == 0) {
            #pragma unroll
            for (int m = 0; m < 4; ++m)
                #pragma unroll
                for (int q = 0; q < 4; ++q) {
                    const int rl = wm * 64 + m * 16 + (l >> 4) * 4 + q;
                    inv_na[s * R_ + rt + rl] = sc[m][q];
                }
        }
    }
}

// ---------------- sim v3: TM=64, dbuf, fused softmax(s) ----------------
__global__ __launch_bounds__(512, 2) void k_sim_v3(
    const u16* __restrict__ xnb, const u16* __restrict__ araw,
    const float* __restrict__ inv_na, u16* __restrict__ whalf, const int half)
{
    __shared__ u16 SmA[2 * 64 * 64];
    __shared__ u16 SmB[2 * 128 * 64];
    const int b   = blockIdx.z;
    const int itl = blockIdx.y * 64;             // local to half (0..448)
    const int it  = half * 512 + itl;
    const int jt  = blockIdx.x * 128;
    const int tid = threadIdx.x, l = tid & 63, wv = tid >> 6;  // 8 waves
    const int wi = wv >> 2, wj = wv & 3;         // 2 x 4 -> wave tile 32 x 32 (per s)
    const u16* __restrict__ Ag = xnb  + (size_t)(b * N_ + it) * 1024;
    const u16* __restrict__ Bg = araw + (size_t)(b * N_ + jt) * 1024;

    f32x4 acc[4][2][2];  // [s][m][n]
    #pragma unroll
    for (int s = 0; s < 4; ++s)
        #pragma unroll
        for (int m = 0; m < 2; ++m)
            #pragma unroll
            for (int n = 0; n < 2; ++n) acc[s][m][n] = (f32x4){0.f, 0.f, 0.f, 0.f};

    auto STAGE = [&](int buf, int t) {
        const int k0 = t * 64;
        {   // A: 64x64 -> 512 chunks, 1/thread
            const int ci = tid;
            const int row = ci >> 3, c = ci & 7, cs = c ^ (row & 7);
            gload16(Ag + (size_t)row * 1024 + k0 + cs * 8, SmA + buf * 4096 + ci * 8);
        }
        #pragma unroll
        for (int i = 0; i < 2; ++i) {   // B: 128x64 -> 1024 chunks, 2/thread
            const int ci = i * 512 + tid;
            const int row = ci >> 3, c = ci & 7, cs = c ^ (row & 7);
            gload16(Bg + (size_t)row * 1024 + k0 + cs * 8, SmB + buf * 8192 + ci * 8);
        }
    };

    STAGE(0, 0);
    #pragma unroll
    for (int s = 0; s < 4; ++s) {
        #pragma unroll
        for (int kk = 0; kk < 4; ++kk) {
            const int t = s * 4 + kk;
            const int cur = t & 1;
            if (t < 15) {
                STAGE(cur ^ 1, t + 1);
                asm volatile("s_waitcnt vmcnt(3)" ::: "memory");
            } else {
                asm volatile("s_waitcnt vmcnt(0)" ::: "memory");
            }
            __builtin_amdgcn_s_barrier();
            __builtin_amdgcn_sched_barrier(0);
            bf16x8 af[2][2], bq[2][2];
            #pragma unroll
            for (int kc = 0; kc < 2; ++kc) {
                #pragma unroll
                for (int m = 0; m < 2; ++m) {
                    const int r = wi * 32 + m * 16 + (l & 15);
                    const int c = (kc * 4 + (l >> 4)) ^ (r & 7);
                    af[kc][m] = *(const bf16x8*)(SmA + cur * 4096 + r * 64 + c * 8);
                }
                #pragma unroll
                for (int n = 0; n < 2; ++n) {
                    const int r = wj * 32 + n * 16 + (l & 15);
                    const int c = (kc * 4 + (l >> 4)) ^ (r & 7);
                    bq[kc][n] = *(const bf16x8*)(SmB + cur * 8192 + r * 64 + c * 8);
                }
            }
            asm volatile("s_waitcnt lgkmcnt(0)" ::: "memory");
            __builtin_amdgcn_s_barrier();
            __builtin_amdgcn_sched_barrier(0);
            #pragma unroll
            for (int kc = 0; kc < 2; ++kc)
                #pragma unroll
                for (int m = 0; m < 2; ++m)
                    #pragma unroll
                    for (int n = 0; n < 2; ++n)
                        acc[s][m][n] = __builtin_amdgcn_mfma_f32_16x16x32_bf16(
                            af[kc][m], bq[kc][n], acc[s][m][n], 0, 0, 0);
        }
    }

    // ---- epilogue: scale by inv_na[j], softmax over s, write w (bf16) ----
    #pragma unroll
    for (int n = 0; n < 2; ++n) {
        const int jg = jt + wj * 32 + n * 16 + (l & 15);
        float inv[4];
        #pragma unroll
        for (int s = 0; s < 4; ++s) inv[s] = inv_na[s * R_ + b * N_ + jg];
        #pragma unroll
        for (int m = 0; m < 2; ++m)
            #pragma unroll
            for (int q = 0; q < 4; ++q) {
                const int il = itl + wi * 32 + m * 16 + (l >> 4) * 4 + q;
                float e[4]; float sum = 0.f;
                #pragma unroll
                for (int s = 0; s < 4; ++s) { e[s] = __expf(acc[s][m][n][q] * inv[s]); sum += e[s]; }
                const float rs = 1.0f / sum;
                #pragma unroll
                for (int s = 0; s < 4; ++s)
                    whalf[((size_t)(s * B_ + b) << 19) + (size_t)il * 1024 + jg] = f2b(e[s] * rs);
            }
    }
}

// ---------------- weighted = w_half . arawT^T (per s,b), 64x128 tile ----------------
__global__ __launch_bounds__(256, 2) void k_gemm_weighted(
    const u16* __restrict__ whalf, const u16* __restrict__ arawT,
    u16* __restrict__ weighted, const int half)
{
    __shared__ u16 SA[2 * 64 * 64];
    __shared__ u16 SB[2 * 128 * 64];
    const int sb = blockIdx.z, s = sb >> 3, b = sb & 7;
    const int mt = blockIdx.y * 64, nt = blockIdx.x * 128;
    f32x4 acc[2][4];
    #pragma unroll
    for (int m = 0; m < 2; ++m)
        #pragma unroll
        for (int n = 0; n < 4; ++n) acc[m][n] = (f32x4){0.f, 0.f, 0.f, 0.f};
    gemm_dbuf<2, 2, 2, 4>(whalf + ((size_t)sb << 19) + (size_t)mt * 1024,
                          arawT + ((size_t)sb << 18) + (size_t)nt * 1024,
                          1024, 1024, 1024, SA, SB, acc);
    const int l = threadIdx.x & 63, wv = threadIdx.x >> 6;
    const int wm = wv >> 1, wn = wv & 1;
    #pragma unroll
    for (int m = 0; m < 2; ++m)
        #pragma unroll
        for (int n = 0; n < 4; ++n)
            #pragma unroll
            for (int q = 0; q < 4; ++q) {
                const int i = half * 512 + mt + wm * 32 + m * 16 + (l >> 4) * 4 + q;
                const int d = nt + wn * 64 + n * 16 + (l & 15);
                weighted[(size_t)(b * N_ + i) * 1024 + s * 256 + d] = f2b(acc[m][n][q]);
            }
}

// ---------------- recon: out = weighted . WrT^T + brsum, 128x128 tile ----------------
__global__ __launch_bounds__(256, 2) void k_gemm_recon(
    const u16* __restrict__ weighted, const u16* __restrict__ WrT,
    const float* __restrict__ brsum, float* __restrict__ out)
{
    __shared__ u16 SA[2 * 128 * 64];
    __shared__ u16 SB[2 * 128 * 64];
    const int mt = blockIdx.y * 128, nt = blockIdx.x * 128;
    f32x4 acc[4][4];
    #pragma unroll
    for (int m = 0; m < 4; ++m)
        #pragma unroll
        for (int n = 0; n < 4; ++n) acc[m][n] = (f32x4){0.f, 0.f, 0.f, 0.f};
    gemm_dbuf<2, 2, 4, 4>(weighted + (size_t)mt * 1024, WrT + (size_t)nt * 1024,
                          1024, 1024, 1024, SA, SB, acc);
    const int l = threadIdx.x & 63, wv = threadIdx.x >> 6;
    const int wm = wv >> 1, wn = wv & 1;
    #pragma unroll
    for (int m = 0; m < 4; ++m)
        #pragma unroll
        for (int n = 0; n < 4; ++n)
            #pragma unroll
            for (int q = 0; q < 4; ++q) {
                const int row = mt + wm * 64 + m * 16 + (l >> 4) * 4 + q;
                const int col = nt + wn * 64 + n * 16 + (l & 15);
                out[(size_t)row * 1024 + col] = acc[m][n][q] + brsum[col];
            }
}

extern "C" void kernel_launch(void* const* d_in, const int* in_sizes, int n_in,
                              void* d_out, int out_size, void* d_ws, size_t ws_size,
                              hipStream_t stream) {
    const float* hx = (const float*)d_in[0];
    const float* ha = (const float*)d_in[1];
    const float* Wp = (const float*)d_in[2];
    const float* bp = (const float*)d_in[3];
    const float* Wr = (const float*)d_in[4];
    const float* br = (const float*)d_in[5];
    float* out = (float*)d_out;

    // Workspace map (117 MiB peak, <= 128 MiB):
    //  [0,16)  hxb (dead after proj) -> weighted
    //  [16,32) hab (dead after proj)
    //  [32,34) WpT  [34,36) WrT  [36,+4K) brsum  [36M+256K,+128K) inv_na
    //  [37,53) xnb   [53,69) araw   [69,85) arawT   [85,117) w_half (32 MiB)
    char* W = (char*)d_ws;
    u16* hxb      = (u16*)(W);
    u16* hab      = (u16*)(W + (16ull << 20));
    u16* WpT      = (u16*)(W + (32ull << 20));
    u16* WrT      = (u16*)(W + (34ull << 20));
    float* brsum  = (float*)(W + (36ull << 20));
    float* inv_na = (float*)(W + (36ull << 20) + (256ull << 10));
    u16* xnb      = (u16*)(W + (37ull << 20));
    u16* araw     = (u16*)(W + (53ull << 20));
    u16* arawT    = (u16*)(W + (69ull << 20));
    u16* whalf    = (u16*)(W + (85ull << 20));
    u16* weighted = (u16*)(W);   // alias hxb

    // 1) casts + weight transposes + bias sum
    k_cast8_2<<<dim3(2 * R_ * H_ / 8 / 256), dim3(256), 0, stream>>>(hx, ha, hxb, hab, R_ * H_ / 8);
    k_tc_wp<<<dim3(16, 4, 4), dim3(256), 0, stream>>>(Wp, WpT);
    k_tc_wr<<<dim3(16, 16), dim3(256), 0, stream>>>(Wr, WrT);
    k_brsum<<<dim3(4), dim3(256), 0, stream>>>(br, brsum);

    // 2) fused projection + norm (BK=32 dbuf, 2 blocks/CU)
    k_proj_norm<<<dim3(64, 4, 2), dim3(512), 0, stream>>>(hxb, hab, WpT, bp, xnb, araw, inv_na);

    // 3) transpose araw -> arawT [(s,b)][d][j]
    k_tc_araw<<<dim3(16, 4, 32), dim3(256), 0, stream>>>(araw, arawT);

    // 4) sim+softmax -> w_half; weighted GEMM, ping-pong over i-halves
    for (int half = 0; half < 2; ++half) {
        k_sim_v3<<<dim3(8, 8, 8), dim3(512), 0, stream>>>(xnb, araw, inv_na, whalf, half);
        k_gemm_weighted<<<dim3(2, 8, 32), dim3(256), 0, stream>>>(whalf, arawT, weighted, half);
    }

    // 5) reconstruct + bias
    k_gemm_recon<<<dim3(8, 64), dim3(256), 0, stream>>>(weighted, WrT, brsum, out);
}